// Round 2
// baseline (324.037 us; speedup 1.0000x reference)
//
#include <hip/hip_runtime.h>
#include <math.h>

#define VAR0 0.1f
#define VAR1 0.2f
#define THRESH 0.5f
#define THETA 0.01f
#define MAXG 64
#define NBINS 2048

// ---------------- fused decode + per-p best-over-g + per-g argmax-over-p ----------------
__global__ void k_iou(const float* __restrict__ arm_loc, const float* __restrict__ priors,
                      const float* __restrict__ targets, const int* __restrict__ num_gts,
                      float* __restrict__ dec, int2* __restrict__ bt,
                      unsigned long long* __restrict__ bp,
                      int B, int P, int G) {
    int b = blockIdx.y;
    int p = blockIdx.x * blockDim.x + threadIdx.x;
    int tid = threadIdx.x;
    __shared__ float st[MAXG * 5];
    __shared__ int sng;
    if (tid == 0) sng = num_gts[b];
    for (int i = tid; i < G * 5; i += blockDim.x) st[i] = targets[(size_t)b * G * 5 + i];
    __syncthreads();
    int ng = sng;
    bool ok = p < P;
    float4 d = make_float4(0.f, 0.f, 0.f, 0.f);
    float areaB = 0.f;
    size_t i = (size_t)b * P + (ok ? p : 0);
    if (ok) {
        float4 l = ((const float4*)arm_loc)[i];
        float4 pr = ((const float4*)priors)[p];
        float cx = pr.x + l.x * VAR0 * pr.z;
        float cy = pr.y + l.y * VAR0 * pr.w;
        float w = pr.z * expf(l.z * VAR1);
        float h = pr.w * expf(l.w * VAR1);
        d.x = cx - w * 0.5f; d.y = cy - h * 0.5f;
        d.z = cx + w * 0.5f; d.w = cy + h * 0.5f;
        ((float4*)dec)[i] = d;
        areaB = (d.z - d.x) * (d.w - d.y);   // post-rounding, bit-matches reference path
    }
    float bov = -2.0f; int bidx = 0;
    int lane = tid & 63;
    for (int g = 0; g < ng; ++g) {
        float t0 = st[g*5], t1 = st[g*5+1], t2 = st[g*5+2], t3 = st[g*5+3];
        float ov = 0.f;
        if (ok) {
            float lt0 = fmaxf(t0, d.x), lt1 = fmaxf(t1, d.y);
            float rb0 = fminf(t2, d.z), rb1 = fminf(t3, d.w);
            float w = rb0 - lt0; if (w < 0.f) w = 0.f;
            float h = rb1 - lt1; if (h < 0.f) h = 0.f;
            float inter = w * h;
            float areaA = (t2 - t0) * (t3 - t1);
            ov = inter / (areaA + areaB - inter);
            if (ov > bov) { bov = ov; bidx = g; }   // first occurrence of max
        }
        unsigned long long key = ok
            ? ((unsigned long long)__float_as_uint(ov) << 32)
              | (unsigned long long)(0xFFFFFFFFu - (unsigned)p)
            : 0ull;
        for (int off = 32; off > 0; off >>= 1) {
            unsigned long long o = __shfl_down(key, (unsigned)off, 64);
            if (o > key) key = o;
        }
        if (lane == 0) atomicMax(&bp[b * G + g], key);
    }
    if (ok) bt[i] = make_int2(__float_as_int(bov), bidx);
}

// ---------------- apply forced matches (ascending g, last wins) ----------------
__global__ void k_fix(const int* __restrict__ num_gts, const unsigned long long* __restrict__ bp,
                      int2* __restrict__ bt, int B, int P, int G) {
    int b = blockIdx.x;
    if (threadIdx.x != 0) return;
    int ng = num_gts[b];
    for (int g = 0; g < ng; ++g) {
        unsigned long long key = bp[b * G + g];
        unsigned p = 0xFFFFFFFFu - (unsigned)(key & 0xFFFFFFFFu);
        bt[(size_t)b * P + p] = make_int2(__float_as_int(2.0f), g);
    }
}

// ---------------- main pass: pos/smoothL1/lse/ce/lc + histogram ----------------
__global__ void k_main(const float* __restrict__ dec, const float* __restrict__ arm_conf,
                       const float* __restrict__ odm_loc, const float* __restrict__ odm_conf,
                       const float* __restrict__ targets, const int* __restrict__ num_gts,
                       const int2* __restrict__ bt,
                       float* __restrict__ lc, float* __restrict__ ce,
                       unsigned char* __restrict__ posm,
                       float* __restrict__ partL, int* __restrict__ npos,
                       unsigned* __restrict__ hist,
                       int B, int P, int C, int G) {
    int b = blockIdx.y;
    int p = blockIdx.x * blockDim.x + threadIdx.x;
    int tid = threadIdx.x;
    __shared__ float st[MAXG * 5];
    __shared__ unsigned lh[NBINS];
    for (int i2 = tid; i2 < NBINS; i2 += blockDim.x) lh[i2] = 0u;
    for (int i2 = tid; i2 < G * 5; i2 += blockDim.x) st[i2] = targets[(size_t)b * G * 5 + i2];
    __syncthreads();
    float lsum = 0.f; int pc = 0;
    if (p < P) {
        size_t i = (size_t)b * P + p;
        int2 m = bt[i];
        float bov = __int_as_float(m.x);
        int bidx = m.y;
        int conf_t = (bov < THRESH) ? 0 : (int)st[bidx*5+4];
        float2 c = ((const float2*)arm_conf)[i];
        float mm = fmaxf(c.x, c.y);
        float e0 = expf(c.x - mm), e1 = expf(c.y - mm);
        float p_obj = e1 / (e0 + e1);
        bool pos = (conf_t > 0) && (p_obj > THETA);
        if (pos) {
            pc = 1;
            float4 d = ((const float4*)dec)[i];
            float pcx = (d.x + d.z) * 0.5f, pcy = (d.y + d.w) * 0.5f;
            float pw = d.z - d.x, ph = d.w - d.y;
            float t0 = st[bidx*5], t1 = st[bidx*5+1], t2 = st[bidx*5+2], t3 = st[bidx*5+3];
            float g0 = ((t0 + t2) * 0.5f - pcx) / (VAR0 * pw);
            float g1 = ((t1 + t3) * 0.5f - pcy) / (VAR0 * ph);
            float g2 = logf((t2 - t0) / pw) / VAR1;
            float g3 = logf((t3 - t1) / ph) / VAR1;
            float4 ol = ((const float4*)odm_loc)[i];
            float dd;
            dd = fabsf(ol.x - g0); lsum += (dd < 1.f) ? 0.5f*dd*dd : dd - 0.5f;
            dd = fabsf(ol.y - g1); lsum += (dd < 1.f) ? 0.5f*dd*dd : dd - 0.5f;
            dd = fabsf(ol.z - g2); lsum += (dd < 1.f) ? 0.5f*dd*dd : dd - 0.5f;
            dd = fabsf(ol.w - g3); lsum += (dd < 1.f) ? 0.5f*dd*dd : dd - 0.5f;
        }
        const float* oc = odm_conf + i * (size_t)C;
        float mx = oc[0];
        for (int j = 1; j < C; ++j) mx = fmaxf(mx, oc[j]);
        float sume = 0.f;
        for (int j = 0; j < C; ++j) sume += expf(oc[j] - mx);
        float lse = mx + logf(sume);
        float cev = lse - oc[conf_t];
        ce[i] = cev;
        float lcv = pos ? 0.f : cev;
        lc[i] = lcv;
        posm[i] = pos ? 1 : 0;
        atomicAdd(&lh[__float_as_uint(lcv) >> 21], 1u);
    }
    __syncthreads();
    unsigned* gh = hist + (size_t)b * NBINS;
    for (int i2 = tid; i2 < NBINS; i2 += blockDim.x) {
        unsigned v = lh[i2];
        if (v) atomicAdd(&gh[i2], v);
    }
    __shared__ float rl[256];
    __shared__ int rc[256];
    rl[tid] = lsum; rc[tid] = pc;
    __syncthreads();
    for (int off = 128; off > 0; off >>= 1) {
        if (tid < off) { rl[tid] += rl[tid+off]; rc[tid] += rc[tid+off]; }
        __syncthreads();
    }
    if (tid == 0) {
        partL[b * gridDim.x + blockIdx.x] = rl[0];
        if (rc[0]) atomicAdd(&npos[b], rc[0]);
    }
}

// ---------------- find the 11-bit bin containing the Kth largest ----------------
__global__ void k_thresh(const unsigned* __restrict__ hist, const int* __restrict__ npos,
                         int* __restrict__ t11, int* __restrict__ k2, int B, int P) {
    int b = blockIdx.x, tid = threadIdx.x;
    const unsigned* h = hist + (size_t)b * NBINS;
    __shared__ unsigned sh[NBINS];
    __shared__ unsigned cs[256];
    for (int i = tid; i < NBINS; i += 256) sh[i] = h[i];
    __syncthreads();
    unsigned s = 0;
    int base = NBINS - 1 - 8 * tid;
    for (int j = 0; j < 8; ++j) s += sh[base - j];
    cs[tid] = s;
    __syncthreads();
    if (tid == 0) {
        long K = 3L * npos[b];
        if (K > P - 1) K = P - 1;
        if (K <= 0) { t11[b] = -1; k2[b] = 0; }
        else {
            long cum = 0; int found = -1; long kk = 0;
            for (int c = 0; c < 256; ++c) {
                if (cum + (long)cs[c] >= K) {
                    int bb = NBINS - 1 - 8 * c;
                    for (int j = 0; j < 8; ++j) {
                        unsigned hv = sh[bb - j];
                        if (cum + (long)hv >= K) { found = bb - j; kk = K - cum; break; }
                        cum += hv;
                    }
                    break;
                }
                cum += cs[c];
            }
            t11[b] = found; k2[b] = (int)kk;
        }
    }
}

// ---------------- gather candidates in the threshold bin ----------------
__global__ void k_collect(const float* __restrict__ lc, const int* __restrict__ t11,
                          unsigned* __restrict__ cand_v, int* __restrict__ cand_i,
                          int* __restrict__ ccnt, int B, int P) {
    int b = blockIdx.y;
    int p = blockIdx.x * blockDim.x + threadIdx.x;
    if (p >= P) return;
    unsigned v = ((const unsigned*)lc)[(size_t)b * P + p];
    if ((int)(v >> 21) == t11[b]) {
        int k = atomicAdd(&ccnt[b], 1);
        cand_v[(size_t)b * P + k] = v;
        cand_i[(size_t)b * P + k] = p;
    }
}

// ---------------- exact threshold (remaining 21 bits) + tie-break index ----------------
__global__ void k_refine(const unsigned* __restrict__ cand_v, const int* __restrict__ cand_i,
                         const int* __restrict__ ccnt, const int* __restrict__ t11,
                         const int* __restrict__ k2v,
                         unsigned* __restrict__ Tb, int* __restrict__ Istar, int B, int P) {
    int b = blockIdx.x, tid = threadIdx.x;
    __shared__ unsigned hist[256];
    __shared__ int sh_k;
    __shared__ unsigned sh_prefix;
    __shared__ int sh_binA;
    int t = t11[b];
    if (t < 0) { if (tid == 0) { Tb[b] = 0xFFFFFFFFu; Istar[b] = -1; } return; }
    int m = ccnt[b];
    const unsigned* cv = cand_v + (size_t)b * P;
    const int* ci = cand_i + (size_t)b * P;
    if (tid == 0) { sh_k = k2v[b]; sh_prefix = ((unsigned)t) << 21; }
    __syncthreads();
    const int shifts[3] = {13, 5, 0};
    const int nbits[3] = {8, 8, 5};
    for (int pass = 0; pass < 3; ++pass) {
        int shift = shifts[pass];
        int bins = 1 << nbits[pass];
        for (int i = tid; i < bins; i += blockDim.x) hist[i] = 0u;
        __syncthreads();
        unsigned pref = sh_prefix;
        unsigned himask = ~((1u << (shift + nbits[pass])) - 1u);
        for (int i = tid; i < m; i += blockDim.x) {
            unsigned v = cv[i];
            if ((v & himask) == (pref & himask))
                atomicAdd(&hist[(v >> shift) & (bins - 1)], 1u);
        }
        __syncthreads();
        if (tid == 0) {
            int k = sh_k; unsigned pr = sh_prefix;
            for (int bin = bins - 1; bin >= 0; --bin) {
                int c = (int)hist[bin];
                if (k <= c) { pr |= ((unsigned)bin) << shift; break; }
                k -= c;
            }
            sh_k = k; sh_prefix = pr;
        }
        __syncthreads();
    }
    unsigned T = sh_prefix;
    // index tie-break: k3-th smallest index among exact equals (idx < 65536, 8+8 bits)
    for (int i = tid; i < 256; i += blockDim.x) hist[i] = 0u;
    __syncthreads();
    for (int i = tid; i < m; i += blockDim.x)
        if (cv[i] == T) atomicAdd(&hist[((unsigned)ci[i] >> 8) & 255u], 1u);
    __syncthreads();
    if (tid == 0) {
        int k = sh_k; int bA = 0;
        for (int bin = 0; bin < 256; ++bin) {
            int c = (int)hist[bin];
            if (k <= c) { bA = bin; break; }
            k -= c;
        }
        sh_binA = bA; sh_k = k;
    }
    __syncthreads();
    int binA = sh_binA;
    for (int i = tid; i < 256; i += blockDim.x) hist[i] = 0u;
    __syncthreads();
    for (int i = tid; i < m; i += blockDim.x)
        if (cv[i] == T && (((unsigned)ci[i] >> 8) & 255u) == (unsigned)binA)
            atomicAdd(&hist[(unsigned)ci[i] & 255u], 1u);
    __syncthreads();
    if (tid == 0) {
        int k = sh_k; int lowb = 0;
        for (int bin = 0; bin < 256; ++bin) {
            int c = (int)hist[bin];
            if (k <= c) { lowb = bin; break; }
            k -= c;
        }
        Tb[b] = T;
        Istar[b] = (binA << 8) | lowb;
    }
}

// ---------------- masked ce sum (parallel, fixed-order) ----------------
__global__ void k_sum(const float* __restrict__ lc, const float* __restrict__ ce,
                      const unsigned char* __restrict__ posm,
                      const unsigned* __restrict__ Tb, const int* __restrict__ Istar,
                      float* __restrict__ partC, int B, int P) {
    int b = blockIdx.y;
    int p = blockIdx.x * blockDim.x + threadIdx.x;
    int tid = threadIdx.x;
    float cs = 0.f;
    if (p < P) {
        size_t i = (size_t)b * P + p;
        unsigned v = ((const unsigned*)lc)[i];
        unsigned T = Tb[b];
        bool sel = posm[i] || (v > T) || (v == T && p <= Istar[b]);
        if (sel) cs = ce[i];
    }
    __shared__ float rs[256];
    rs[tid] = cs;
    __syncthreads();
    for (int off = 128; off > 0; off >>= 1) {
        if (tid < off) rs[tid] += rs[tid + off];
        __syncthreads();
    }
    if (tid == 0) partC[b * gridDim.x + blockIdx.x] = rs[0];
}

// ---------------- final deterministic reduce + divide ----------------
__global__ void k_final(const float* __restrict__ partL, const float* __restrict__ partC,
                        const int* __restrict__ npos, int nPart,
                        float* __restrict__ out, int B) {
    __shared__ float sL[256];
    __shared__ float sC[256];
    __shared__ int   sN[256];
    int tid = threadIdx.x;
    float aL = 0.f, aC = 0.f; int aN = 0;
    for (int i = tid; i < nPart; i += 256) { aL += partL[i]; aC += partC[i]; }
    for (int i = tid; i < B; i += 256) aN += npos[i];
    sL[tid] = aL; sC[tid] = aC; sN[tid] = aN;
    __syncthreads();
    for (int off = 128; off > 0; off >>= 1) {
        if (tid < off) { sL[tid] += sL[tid+off]; sC[tid] += sC[tid+off]; sN[tid] += sN[tid+off]; }
        __syncthreads();
    }
    if (tid == 0) {
        float N = (float)sN[0];
        out[0] = sL[0] / N;
        out[1] = sC[0] / N;
    }
}

extern "C" void kernel_launch(void* const* d_in, const int* in_sizes, int n_in,
                              void* d_out, int out_size, void* d_ws, size_t ws_size,
                              hipStream_t stream) {
    const float* arm_loc  = (const float*)d_in[0];
    const float* arm_conf = (const float*)d_in[1];
    const float* odm_loc  = (const float*)d_in[2];
    const float* odm_conf = (const float*)d_in[3];
    const float* priors   = (const float*)d_in[4];
    const float* targets  = (const float*)d_in[5];
    const int*   num_gts  = (const int*)d_in[6];
    float* out = (float*)d_out;

    int B = in_sizes[6];
    int P = in_sizes[4] / 4;
    int C = in_sizes[3] / (B * P);
    int G = in_sizes[5] / (B * 5);

    char* ws = (char*)d_ws;
    size_t off = 0;
    auto alloc = [&](size_t bytes) -> void* {
        void* ptr = ws + off;
        off = (off + bytes + 255) & ~(size_t)255;
        return ptr;
    };
    // ---- zero-initialized region (single memset) ----
    unsigned* hist = (unsigned*)alloc((size_t)B * NBINS * sizeof(unsigned));
    unsigned long long* bp = (unsigned long long*)alloc((size_t)B * G * 8);
    int* npos = (int*)alloc((size_t)B * sizeof(int));
    int* ccnt = (int*)alloc((size_t)B * sizeof(int));
    size_t zero_bytes = off;
    // ---- rest ----
    float* dec = (float*)alloc((size_t)B * P * 4 * sizeof(float));
    int2* bt   = (int2*)alloc((size_t)B * P * sizeof(int2));
    float* lc  = (float*)alloc((size_t)B * P * sizeof(float));
    float* ce  = (float*)alloc((size_t)B * P * sizeof(float));
    unsigned char* posm = (unsigned char*)alloc((size_t)B * P);
    unsigned* cand_v = (unsigned*)alloc((size_t)B * P * sizeof(unsigned));
    int* cand_i = (int*)alloc((size_t)B * P * sizeof(int));
    int NBX = (P + 255) / 256;
    float* partL = (float*)alloc((size_t)B * NBX * sizeof(float));
    float* partC = (float*)alloc((size_t)B * NBX * sizeof(float));
    int* t11 = (int*)alloc((size_t)B * sizeof(int));
    int* k2  = (int*)alloc((size_t)B * sizeof(int));
    unsigned* Tb = (unsigned*)alloc((size_t)B * sizeof(unsigned));
    int* Istar = (int*)alloc((size_t)B * sizeof(int));

    hipMemsetAsync(ws, 0, zero_bytes, stream);

    k_iou<<<dim3(NBX, B), 256, 0, stream>>>(arm_loc, priors, targets, num_gts, dec, bt, bp, B, P, G);
    k_fix<<<B, 64, 0, stream>>>(num_gts, bp, bt, B, P, G);
    k_main<<<dim3(NBX, B), 256, 0, stream>>>(dec, arm_conf, odm_loc, odm_conf, targets, num_gts,
                                             bt, lc, ce, posm, partL, npos, hist, B, P, C, G);
    k_thresh<<<B, 256, 0, stream>>>(hist, npos, t11, k2, B, P);
    k_collect<<<dim3(NBX, B), 256, 0, stream>>>(lc, t11, cand_v, cand_i, ccnt, B, P);
    k_refine<<<B, 256, 0, stream>>>(cand_v, cand_i, ccnt, t11, k2, Tb, Istar, B, P);
    k_sum<<<dim3(NBX, B), 256, 0, stream>>>(lc, ce, posm, Tb, Istar, partC, B, P);
    k_final<<<1, 256, 0, stream>>>(partL, partC, npos, B * NBX, out, B);
}

// Round 3
// 139.813 us; speedup vs baseline: 2.3177x; 2.3177x over previous
//
#include <hip/hip_runtime.h>
#include <math.h>

#define VAR0 0.1f
#define VAR1 0.2f
#define THRESH 0.5f
#define THETA 0.01f
#define MAXG 64
#define BLK 256
#define SELT 1024
#define NCH 16   // ceil(P/SELT) for P=16320

// ---------------- fused decode + per-p best-over-g; per-(g,wave) winner to scratch ----------------
__global__ void k_iou(const float* __restrict__ arm_loc, const float* __restrict__ priors,
                      const float* __restrict__ targets, const int* __restrict__ num_gts,
                      float* __restrict__ dec, int2* __restrict__ bt,
                      unsigned long long* __restrict__ bpw,
                      int B, int P, int G, int W) {
    int b = blockIdx.y;
    int p = blockIdx.x * blockDim.x + threadIdx.x;
    int tid = threadIdx.x;
    int lane = tid & 63;
    int wv_id = blockIdx.x * (blockDim.x >> 6) + (tid >> 6);
    __shared__ float st[MAXG * 5];
    __shared__ int sng;
    if (tid == 0) sng = num_gts[b];
    for (int i = tid; i < G * 5; i += blockDim.x) st[i] = targets[(size_t)b * G * 5 + i];
    __syncthreads();
    int ng = sng;
    bool ok = p < P;
    float4 d = make_float4(0.f, 0.f, 0.f, 0.f);
    float areaB = 0.f;
    size_t i = (size_t)b * P + (ok ? p : 0);
    if (ok) {
        float4 l = ((const float4*)arm_loc)[i];
        float4 pr = ((const float4*)priors)[p];
        float cx = pr.x + l.x * VAR0 * pr.z;
        float cy = pr.y + l.y * VAR0 * pr.w;
        float w = pr.z * expf(l.z * VAR1);
        float h = pr.w * expf(l.w * VAR1);
        d.x = cx - w * 0.5f; d.y = cy - h * 0.5f;
        d.z = cx + w * 0.5f; d.w = cy + h * 0.5f;
        ((float4*)dec)[i] = d;
        areaB = (d.z - d.x) * (d.w - d.y);
    }
    float bov = -2.0f; int bidx = 0;
    for (int g = 0; g < ng; ++g) {
        float t0 = st[g*5], t1 = st[g*5+1], t2 = st[g*5+2], t3 = st[g*5+3];
        float ov = 0.f;
        if (ok) {
            float lt0 = fmaxf(t0, d.x), lt1 = fmaxf(t1, d.y);
            float rb0 = fminf(t2, d.z), rb1 = fminf(t3, d.w);
            float w = rb0 - lt0; if (w < 0.f) w = 0.f;
            float h = rb1 - lt1; if (h < 0.f) h = 0.f;
            float inter = w * h;
            float areaA = (t2 - t0) * (t3 - t1);
            ov = inter / (areaA + areaB - inter);
            if (ov > bov) { bov = ov; bidx = g; }   // first occurrence of max over g
        }
        unsigned long long key = ok
            ? ((unsigned long long)__float_as_uint(ov) << 32)
              | (unsigned long long)(0xFFFFFFFFu - (unsigned)p)
            : 0ull;
        for (int off = 32; off > 0; off >>= 1) {
            unsigned long long o = __shfl_down(key, (unsigned)off, 64);
            if (o > key) key = o;
        }
        if (lane == 0) bpw[((size_t)(b * G + g)) * W + wv_id] = key;
    }
    if (ok) bt[i] = make_int2(__float_as_int(bov), bidx);
}

// ---------------- reduce per-wave winners, apply forced matches (ascending g, last wins) ----------------
__global__ void k_fix(const int* __restrict__ num_gts, const unsigned long long* __restrict__ bpw,
                      int2* __restrict__ bt, int B, int P, int G, int W) {
    int b = blockIdx.x;
    int tid = threadIdx.x;
    int lane = tid & 63, wid = tid >> 6;
    __shared__ unsigned long long wk[4];
    __shared__ int fp[MAXG];
    int ng = num_gts[b];
    for (int g = 0; g < ng; ++g) {
        const unsigned long long* src = bpw + ((size_t)(b * G + g)) * W;
        unsigned long long key = 0ull;
        for (int j = tid; j < W; j += blockDim.x) {
            unsigned long long v = src[j];
            if (v > key) key = v;
        }
        for (int off = 32; off > 0; off >>= 1) {
            unsigned long long o = __shfl_down(key, (unsigned)off, 64);
            if (o > key) key = o;
        }
        if (lane == 0) wk[wid] = key;
        __syncthreads();
        if (tid == 0) {
            unsigned long long m = wk[0];
            for (int w = 1; w < 4; ++w) if (wk[w] > m) m = wk[w];
            fp[g] = (int)(0xFFFFFFFFu - (unsigned)(m & 0xFFFFFFFFull));
        }
        __syncthreads();
    }
    if (tid == 0)
        for (int g = 0; g < ng; ++g)
            bt[(size_t)b * P + fp[g]] = make_int2(__float_as_int(2.0f), g);
}

// ---------------- main pass: pos/smoothL1/lse/ce/lc (odm_conf LDS-staged) ----------------
__global__ void k_main(const float* __restrict__ dec, const float* __restrict__ arm_conf,
                       const float* __restrict__ odm_loc, const float* __restrict__ odm_conf,
                       const float* __restrict__ targets,
                       const int2* __restrict__ bt,
                       float* __restrict__ lc, float* __restrict__ ce,
                       unsigned char* __restrict__ posm,
                       float* __restrict__ partL, int* __restrict__ partN,
                       int B, int P, int C, int G) {
    int b = blockIdx.y;
    int p0 = blockIdx.x * BLK;
    int tid = threadIdx.x;
    int p = p0 + tid;
    __shared__ float st[MAXG * 5];
    __shared__ float oc_s[BLK * 21];   // assumes C == 21
    for (int i2 = tid; i2 < G * 5; i2 += BLK) st[i2] = targets[(size_t)b * G * 5 + i2];
    int nrows = P - p0; if (nrows > BLK) nrows = BLK;
    int nf = nrows * C;
    const float* ocb = odm_conf + ((size_t)b * P + p0) * C;   // 16B aligned for C=21, BLK=256
    int nf4 = nf >> 2;
    const float4* ocb4 = (const float4*)ocb;
    for (int i2 = tid; i2 < nf4; i2 += BLK) ((float4*)oc_s)[i2] = ocb4[i2];
    if (tid < (nf & 3)) oc_s[(nf4 << 2) + tid] = ocb[(nf4 << 2) + tid];
    __syncthreads();
    float lsum = 0.f; int pc = 0;
    if (p < P) {
        size_t i = (size_t)b * P + p;
        int2 m = bt[i];
        float bov = __int_as_float(m.x);
        int bidx = m.y;
        int conf_t = (bov < THRESH) ? 0 : (int)st[bidx*5+4];
        float2 c = ((const float2*)arm_conf)[i];
        float mm = fmaxf(c.x, c.y);
        float e0 = expf(c.x - mm), e1 = expf(c.y - mm);
        float p_obj = e1 / (e0 + e1);
        bool pos = (conf_t > 0) && (p_obj > THETA);
        if (pos) {
            pc = 1;
            float4 d = ((const float4*)dec)[i];
            float pcx = (d.x + d.z) * 0.5f, pcy = (d.y + d.w) * 0.5f;
            float pw = d.z - d.x, ph = d.w - d.y;
            float t0 = st[bidx*5], t1 = st[bidx*5+1], t2 = st[bidx*5+2], t3 = st[bidx*5+3];
            float g0 = ((t0 + t2) * 0.5f - pcx) / (VAR0 * pw);
            float g1 = ((t1 + t3) * 0.5f - pcy) / (VAR0 * ph);
            float g2 = logf((t2 - t0) / pw) / VAR1;
            float g3 = logf((t3 - t1) / ph) / VAR1;
            float4 ol = ((const float4*)odm_loc)[i];
            float dd;
            dd = fabsf(ol.x - g0); lsum += (dd < 1.f) ? 0.5f*dd*dd : dd - 0.5f;
            dd = fabsf(ol.y - g1); lsum += (dd < 1.f) ? 0.5f*dd*dd : dd - 0.5f;
            dd = fabsf(ol.z - g2); lsum += (dd < 1.f) ? 0.5f*dd*dd : dd - 0.5f;
            dd = fabsf(ol.w - g3); lsum += (dd < 1.f) ? 0.5f*dd*dd : dd - 0.5f;
        }
        const float* oc = oc_s + tid * C;
        float mx = oc[0];
        for (int j = 1; j < C; ++j) mx = fmaxf(mx, oc[j]);
        float sume = 0.f;
        for (int j = 0; j < C; ++j) sume += expf(oc[j] - mx);
        float lse = mx + logf(sume);
        float cev = lse - oc[conf_t];
        ce[i] = cev;
        lc[i] = pos ? 0.f : cev;
        posm[i] = pos ? 1 : 0;
    }
    __shared__ float rl[BLK];
    __shared__ int rc[BLK];
    rl[tid] = lsum; rc[tid] = pc;
    __syncthreads();
    for (int off = BLK/2; off > 0; off >>= 1) {
        if (tid < off) { rl[tid] += rl[tid+off]; rc[tid] += rc[tid+off]; }
        __syncthreads();
    }
    if (tid == 0) {
        partL[b * gridDim.x + blockIdx.x] = rl[0];
        partN[b * gridDim.x + blockIdx.x] = rc[0];
    }
}

// ---------------- per-batch: register-resident bitwise radix-select + tie-break + masked ce sum ----------------
__global__ __launch_bounds__(SELT) void k_select(
        const float* __restrict__ lc, const float* __restrict__ ce,
        const unsigned char* __restrict__ posm,
        const int* __restrict__ partN, int NBX,
        float* __restrict__ partC, int* __restrict__ npos, int P) {
    int b = blockIdx.x;
    int tid = threadIdx.x;
    int lane = tid & 63, wid = tid >> 6;
    __shared__ int wvi[16];
    __shared__ float wvf[16];
    __shared__ int sh_base[16];
    __shared__ unsigned sh_pref;
    __shared__ int sh_k, sh_istar, sh_cum, sh_npos;

    // npos_b = sum of per-block partials (deterministic)
    int c0 = 0;
    for (int j = tid; j < NBX; j += SELT) c0 += partN[b * NBX + j];
    for (int off = 32; off > 0; off >>= 1) c0 += __shfl_down(c0, (unsigned)off, 64);
    if (lane == 0) wvi[wid] = c0;
    __syncthreads();
    if (tid < 64) {
        int v = (tid < 16) ? wvi[tid] : 0;
        for (int off = 32; off > 0; off >>= 1) v += __shfl_down(v, (unsigned)off, 64);
        if (tid == 0) sh_npos = v;
    }
    __syncthreads();
    int npos_b = sh_npos;
    long K = 3L * npos_b;
    if (K > P - 1) K = P - 1;

    // load this batch's lc bit patterns into registers (static indexing)
    unsigned lv[NCH];
    const unsigned* lcb = (const unsigned*)lc + (size_t)b * P;
    #pragma unroll
    for (int c = 0; c < NCH; ++c) {
        int i = c * SELT + tid;
        lv[c] = (i < P) ? lcb[i] : 0u;
    }

    unsigned T; int krem; int istar = -1;
    if (K <= 0) {
        T = 0xFFFFFFFFu; krem = 0;
    } else {
        if (tid == 0) { sh_pref = 0u; sh_k = (int)K; }
        __syncthreads();
        for (int bit = 30; bit >= 0; --bit) {   // bit31 is always 0 (lc >= 0)
            unsigned pref = sh_pref;
            int kk = sh_k;
            unsigned long long hi = (unsigned long long)pref >> (bit + 1);
            int cnt = 0;
            #pragma unroll
            for (int c = 0; c < NCH; ++c) {
                int i = c * SELT + tid;
                unsigned v = lv[c];
                bool pred = (i < P) && (((unsigned long long)v >> (bit + 1)) == hi)
                            && ((v >> bit) & 1u);
                cnt += pred ? 1 : 0;
            }
            for (int off = 32; off > 0; off >>= 1) cnt += __shfl_down(cnt, (unsigned)off, 64);
            if (lane == 0) wvi[wid] = cnt;
            __syncthreads();
            if (tid < 64) {
                int v = (tid < 16) ? wvi[tid] : 0;
                for (int off = 32; off > 0; off >>= 1) v += __shfl_down(v, (unsigned)off, 64);
                if (tid == 0) {
                    if (kk <= v) sh_pref = pref | (1u << bit);
                    else sh_k = kk - v;
                }
            }
            __syncthreads();
        }
        T = sh_pref; krem = sh_k;
        // tie-break: krem-th smallest index among exact equals (ordered chunk scan)
        if (tid == 0) { sh_istar = -1; sh_cum = 0; }
        __syncthreads();
        for (int c = 0; c < NCH; ++c) {
            int i = c * SELT + tid;
            bool eq = (i < P) && (lv[c] == T);
            unsigned long long m = __ballot(eq);
            if (lane == 0) wvi[wid] = (int)__popcll(m);
            __syncthreads();
            if (tid < 64) {
                int v = (tid < 16) ? wvi[tid] : 0;
                for (int off = 1; off < 16; off <<= 1) {
                    int o = __shfl_up(v, (unsigned)off, 64);
                    if (lane >= off) v += o;
                }
                if (tid < 16) sh_base[tid] = v;   // inclusive scan of wave counts
            }
            __syncthreads();
            int cum = sh_cum;
            int base = (wid == 0) ? 0 : sh_base[wid - 1];
            if (eq) {
                int r = cum + base + (int)__popcll(m & ((1ull << lane) - 1ull));
                if (r == krem - 1) sh_istar = i;
            }
            __syncthreads();
            if (tid == 0) sh_cum = cum + sh_base[15];
            __syncthreads();
            if (sh_cum >= krem) break;   // uniform
        }
        __syncthreads();
        istar = sh_istar;
    }

    // masked ce sum (fixed-order tree)
    float cs = 0.f;
    const float* ceb = ce + (size_t)b * P;
    const unsigned char* pb = posm + (size_t)b * P;
    #pragma unroll
    for (int c = 0; c < NCH; ++c) {
        int i = c * SELT + tid;
        if (i < P) {
            unsigned v = lv[c];
            float cv = ceb[i];
            bool sel = (pb[i] != 0) || (v > T) || (v == T && i <= istar);
            if (sel) cs += cv;
        }
    }
    for (int off = 32; off > 0; off >>= 1) cs += __shfl_down(cs, (unsigned)off, 64);
    if (lane == 0) wvf[wid] = cs;
    __syncthreads();
    if (tid < 64) {
        float v = (tid < 16) ? wvf[tid] : 0.f;
        for (int off = 32; off > 0; off >>= 1) v += __shfl_down(v, (unsigned)off, 64);
        if (tid == 0) { partC[b] = v; npos[b] = npos_b; }
    }
}

// ---------------- final deterministic reduce + divide ----------------
__global__ void k_final(const float* __restrict__ partL, const float* __restrict__ partC,
                        const int* __restrict__ npos, int nPart,
                        float* __restrict__ out, int B) {
    __shared__ float sL[256];
    __shared__ float sC[256];
    __shared__ int   sN[256];
    int tid = threadIdx.x;
    float aL = 0.f, aC = 0.f; int aN = 0;
    for (int i = tid; i < nPart; i += 256) aL += partL[i];
    for (int i = tid; i < B; i += 256) { aC += partC[i]; aN += npos[i]; }
    sL[tid] = aL; sC[tid] = aC; sN[tid] = aN;
    __syncthreads();
    for (int off = 128; off > 0; off >>= 1) {
        if (tid < off) { sL[tid] += sL[tid+off]; sC[tid] += sC[tid+off]; sN[tid] += sN[tid+off]; }
        __syncthreads();
    }
    if (tid == 0) {
        float N = (float)sN[0];
        out[0] = sL[0] / N;
        out[1] = sC[0] / N;
    }
}

extern "C" void kernel_launch(void* const* d_in, const int* in_sizes, int n_in,
                              void* d_out, int out_size, void* d_ws, size_t ws_size,
                              hipStream_t stream) {
    const float* arm_loc  = (const float*)d_in[0];
    const float* arm_conf = (const float*)d_in[1];
    const float* odm_loc  = (const float*)d_in[2];
    const float* odm_conf = (const float*)d_in[3];
    const float* priors   = (const float*)d_in[4];
    const float* targets  = (const float*)d_in[5];
    const int*   num_gts  = (const int*)d_in[6];
    float* out = (float*)d_out;

    int B = in_sizes[6];
    int P = in_sizes[4] / 4;
    int C = in_sizes[3] / (B * P);
    int G = in_sizes[5] / (B * 5);
    int NBX = (P + BLK - 1) / BLK;
    int W = NBX * (BLK / 64);   // waves per batch in k_iou

    char* ws = (char*)d_ws;
    size_t off = 0;
    auto alloc = [&](size_t bytes) -> void* {
        void* ptr = ws + off;
        off = (off + bytes + 255) & ~(size_t)255;
        return ptr;
    };
    float* dec = (float*)alloc((size_t)B * P * 4 * sizeof(float));
    int2* bt   = (int2*)alloc((size_t)B * P * sizeof(int2));
    unsigned long long* bpw = (unsigned long long*)alloc((size_t)B * G * W * 8);
    float* lc  = (float*)alloc((size_t)B * P * sizeof(float));
    float* ce  = (float*)alloc((size_t)B * P * sizeof(float));
    unsigned char* posm = (unsigned char*)alloc((size_t)B * P);
    float* partL = (float*)alloc((size_t)B * NBX * sizeof(float));
    int* partN   = (int*)alloc((size_t)B * NBX * sizeof(int));
    float* partC = (float*)alloc((size_t)B * sizeof(float));
    int* npos    = (int*)alloc((size_t)B * sizeof(int));

    k_iou<<<dim3(NBX, B), BLK, 0, stream>>>(arm_loc, priors, targets, num_gts, dec, bt, bpw, B, P, G, W);
    k_fix<<<B, BLK, 0, stream>>>(num_gts, bpw, bt, B, P, G, W);
    k_main<<<dim3(NBX, B), BLK, 0, stream>>>(dec, arm_conf, odm_loc, odm_conf, targets,
                                             bt, lc, ce, posm, partL, partN, B, P, C, G);
    k_select<<<B, SELT, 0, stream>>>(lc, ce, posm, partN, NBX, partC, npos, P);
    k_final<<<1, 256, 0, stream>>>(partL, partC, npos, B * NBX, out, B);
}

// Round 4
// 124.218 us; speedup vs baseline: 2.6086x; 1.1255x over previous
//
#include <hip/hip_runtime.h>
#include <math.h>

#define VAR0 0.1f
#define VAR1 0.2f
#define THRESH 0.5f
#define THETA 0.01f
#define MAXG 64
#define BLK 256
#define SELT 1024
#define NCH 16     // ceil(P/SELT) for P=16320
#define NB 4096    // histogram bins
#define CAP 2048   // candidate buffer

// ---------------- fused decode + per-p best-over-g + per-g argmax via atomicMax ----------------
__global__ void k_iou(const float* __restrict__ arm_loc, const float* __restrict__ priors,
                      const float* __restrict__ targets, const int* __restrict__ num_gts,
                      float* __restrict__ dec, unsigned long long* __restrict__ bt,
                      unsigned long long* __restrict__ bp,
                      int B, int P, int G) {
    int b = blockIdx.y;
    int p = blockIdx.x * blockDim.x + threadIdx.x;
    int tid = threadIdx.x;
    int lane = tid & 63;
    __shared__ float st[MAXG * 5];
    __shared__ int sng;
    if (tid == 0) sng = num_gts[b];
    for (int i = tid; i < G * 5; i += blockDim.x) st[i] = targets[(size_t)b * G * 5 + i];
    __syncthreads();
    int ng = sng;
    bool ok = p < P;
    float4 d = make_float4(0.f, 0.f, 0.f, 0.f);
    float areaB = 0.f;
    size_t i = (size_t)b * P + (ok ? p : 0);
    if (ok) {
        float4 l = ((const float4*)arm_loc)[i];
        float4 pr = ((const float4*)priors)[p];
        float cx = pr.x + l.x * VAR0 * pr.z;
        float cy = pr.y + l.y * VAR0 * pr.w;
        float w = pr.z * expf(l.z * VAR1);
        float h = pr.w * expf(l.w * VAR1);
        d.x = cx - w * 0.5f; d.y = cy - h * 0.5f;
        d.z = cx + w * 0.5f; d.w = cy + h * 0.5f;
        ((float4*)dec)[i] = d;
        areaB = (d.z - d.x) * (d.w - d.y);
    }
    int wavebase = blockIdx.x * (int)blockDim.x + (tid & ~63);
    float bov = -2.0f; int bidx = 0;
    for (int g = 0; g < ng; ++g) {
        float t0 = st[g*5], t1 = st[g*5+1], t2 = st[g*5+2], t3 = st[g*5+3];
        float ov = -1.0f;
        if (ok) {
            float lt0 = fmaxf(t0, d.x), lt1 = fmaxf(t1, d.y);
            float rb0 = fminf(t2, d.z), rb1 = fminf(t3, d.w);
            float w = rb0 - lt0; if (w < 0.f) w = 0.f;
            float h = rb1 - lt1; if (h < 0.f) h = 0.f;
            float inter = w * h;
            float areaA = (t2 - t0) * (t3 - t1);
            ov = inter / (areaA + areaB - inter);
            if (ov > bov) { bov = ov; bidx = g; }   // first occurrence of max over g
        }
        float om = ov;
        for (int off = 32; off > 0; off >>= 1) om = fmaxf(om, __shfl_xor(om, off, 64));
        unsigned long long mask = __ballot(ov == om);   // !ok lanes have ov=-1 < om when om>=0
        if (lane == 0 && om >= 0.f) {
            int p_win = wavebase + (int)__builtin_ctzll(mask);
            unsigned long long key = ((unsigned long long)__float_as_uint(om) << 32)
                                   | (unsigned long long)(0xFFFFFFFFu - (unsigned)p_win);
            atomicMax(&bp[b * G + g], key);
        }
    }
    if (ok)
        bt[i] = ((unsigned long long)__float_as_uint(bov) << 32) | (unsigned)bidx;
}

// ---------------- forced matches: atomicMax with bov=2.0 packed high; max-g = last-wins ----------------
__global__ void k_fix(const int* __restrict__ num_gts, const unsigned long long* __restrict__ bp,
                      unsigned long long* __restrict__ bt, int B, int P, int G) {
    int b = blockIdx.x;
    int g = threadIdx.x;
    if (g >= num_gts[b]) return;
    unsigned long long key = bp[b * G + g];
    unsigned p = 0xFFFFFFFFu - (unsigned)(key & 0xFFFFFFFFull);
    unsigned long long fkey = ((unsigned long long)0x40000000u << 32) | (unsigned)g;  // 2.0f hi
    atomicMax(&bt[(size_t)b * P + p], fkey);
}

// ---------------- main pass: pos/smoothL1/lse/ce/lc (odm_conf LDS-staged) ----------------
__global__ void k_main(const float* __restrict__ dec, const float* __restrict__ arm_conf,
                       const float* __restrict__ odm_loc, const float* __restrict__ odm_conf,
                       const float* __restrict__ targets,
                       const unsigned long long* __restrict__ bt,
                       float* __restrict__ lc, float* __restrict__ ce,
                       unsigned char* __restrict__ posm,
                       float* __restrict__ partL, int* __restrict__ partN,
                       int B, int P, int C, int G) {
    int b = blockIdx.y;
    int p0 = blockIdx.x * BLK;
    int tid = threadIdx.x;
    int p = p0 + tid;
    __shared__ float st[MAXG * 5];
    __shared__ float oc_s[BLK * 21];   // assumes C == 21
    for (int i2 = tid; i2 < G * 5; i2 += BLK) st[i2] = targets[(size_t)b * G * 5 + i2];
    int nrows = P - p0; if (nrows > BLK) nrows = BLK;
    int nf = nrows * C;
    const float* ocb = odm_conf + ((size_t)b * P + p0) * C;
    int nf4 = nf >> 2;
    const float4* ocb4 = (const float4*)ocb;
    for (int i2 = tid; i2 < nf4; i2 += BLK) ((float4*)oc_s)[i2] = ocb4[i2];
    if (tid < (nf & 3)) oc_s[(nf4 << 2) + tid] = ocb[(nf4 << 2) + tid];
    __syncthreads();
    float lsum = 0.f; int pc = 0;
    if (p < P) {
        size_t i = (size_t)b * P + p;
        unsigned long long mv = bt[i];
        float bov = __uint_as_float((unsigned)(mv >> 32));
        int bidx = (int)(mv & 0xFFFFFFFFull);
        int conf_t = (bov < THRESH) ? 0 : (int)st[bidx*5+4];
        float2 c = ((const float2*)arm_conf)[i];
        float mm = fmaxf(c.x, c.y);
        float e0 = expf(c.x - mm), e1 = expf(c.y - mm);
        float p_obj = e1 / (e0 + e1);
        bool pos = (conf_t > 0) && (p_obj > THETA);
        if (pos) {
            pc = 1;
            float4 d = ((const float4*)dec)[i];
            float pcx = (d.x + d.z) * 0.5f, pcy = (d.y + d.w) * 0.5f;
            float pw = d.z - d.x, ph = d.w - d.y;
            float t0 = st[bidx*5], t1 = st[bidx*5+1], t2 = st[bidx*5+2], t3 = st[bidx*5+3];
            float g0 = ((t0 + t2) * 0.5f - pcx) / (VAR0 * pw);
            float g1 = ((t1 + t3) * 0.5f - pcy) / (VAR0 * ph);
            float g2 = logf((t2 - t0) / pw) / VAR1;
            float g3 = logf((t3 - t1) / ph) / VAR1;
            float4 ol = ((const float4*)odm_loc)[i];
            float dd;
            dd = fabsf(ol.x - g0); lsum += (dd < 1.f) ? 0.5f*dd*dd : dd - 0.5f;
            dd = fabsf(ol.y - g1); lsum += (dd < 1.f) ? 0.5f*dd*dd : dd - 0.5f;
            dd = fabsf(ol.z - g2); lsum += (dd < 1.f) ? 0.5f*dd*dd : dd - 0.5f;
            dd = fabsf(ol.w - g3); lsum += (dd < 1.f) ? 0.5f*dd*dd : dd - 0.5f;
        }
        const float* oc = oc_s + tid * C;
        float mx = oc[0];
        for (int j = 1; j < C; ++j) mx = fmaxf(mx, oc[j]);
        float sume = 0.f;
        for (int j = 0; j < C; ++j) sume += expf(oc[j] - mx);
        float lse = mx + logf(sume);
        float cev = lse - oc[conf_t];
        ce[i] = cev;
        lc[i] = pos ? 0.f : cev;
        posm[i] = pos ? 1 : 0;
    }
    __shared__ float rl[BLK];
    __shared__ int rc[BLK];
    rl[tid] = lsum; rc[tid] = pc;
    __syncthreads();
    for (int off = BLK/2; off > 0; off >>= 1) {
        if (tid < off) { rl[tid] += rl[tid+off]; rc[tid] += rc[tid+off]; }
        __syncthreads();
    }
    if (tid == 0) {
        partL[b * gridDim.x + blockIdx.x] = rl[0];
        partN[b * gridDim.x + blockIdx.x] = rc[0];
    }
}

// ---------------- per-batch: histogram-select Kth-largest + tie-break + masked ce sum ----------------
__global__ __launch_bounds__(SELT) void k_select(
        const float* __restrict__ lc, const float* __restrict__ ce,
        const unsigned char* __restrict__ posm,
        const int* __restrict__ partN, int NBX,
        float* __restrict__ partC, int* __restrict__ npos, int P) {
    int b = blockIdx.x;
    int tid = threadIdx.x;
    int lane = tid & 63, wid = tid >> 6;
    __shared__ unsigned hist[NB];
    __shared__ float cv[CAP];
    __shared__ int   ci[CAP];
    __shared__ int   sums[SELT];
    __shared__ int   redi[16];
    __shared__ float redf[16];
    __shared__ int sh_base[16];
    __shared__ int sh_m, sh_b1, sh_k1, sh_npos, sh_istar, sh_kk, sh_cum;
    __shared__ unsigned sh_T, sh_pref;
    __shared__ float sh_mx;

    // npos_b from per-block partials (deterministic)
    int c0 = 0;
    for (int j = tid; j < NBX; j += SELT) c0 += partN[b * NBX + j];
    for (int off = 32; off > 0; off >>= 1) c0 += __shfl_down(c0, (unsigned)off, 64);
    if (lane == 0) redi[wid] = c0;
    __syncthreads();
    if (tid < 64) {
        int v = (tid < 16) ? redi[tid] : 0;
        for (int off = 32; off > 0; off >>= 1) v += __shfl_down(v, (unsigned)off, 64);
        if (tid == 0) sh_npos = v;
    }
    __syncthreads();
    int npos_b = sh_npos;
    long K = 3L * npos_b;
    if (K > P - 1) K = P - 1;

    // register-resident lc bit patterns
    unsigned lv[NCH];
    const unsigned* lcb = (const unsigned*)lc + (size_t)b * P;
    #pragma unroll
    for (int c = 0; c < NCH; ++c) {
        int i = c * SELT + tid;
        lv[c] = (i < P) ? lcb[i] : 0u;
    }

    unsigned uT = 0xFFFFFFFFu; int istar = -1;
    if (K > 0) {
        // batch max
        float mx = 0.f;
        #pragma unroll
        for (int c = 0; c < NCH; ++c) mx = fmaxf(mx, __uint_as_float(lv[c]));
        for (int off = 32; off > 0; off >>= 1) mx = fmaxf(mx, __shfl_xor(mx, off, 64));
        if (lane == 0) redf[wid] = mx;
        __syncthreads();
        if (tid == 0) {
            float v = redf[0];
            for (int w = 1; w < 16; ++w) v = fmaxf(v, redf[w]);
            sh_mx = v;
        }
        __syncthreads();
        float vmax = sh_mx;
        float scale = (vmax > 0.f) ? ((float)NB / vmax) : 0.f;

        // histogram (linear bins -> near-uniform, low contention)
        for (int j = tid; j < NB; j += SELT) hist[j] = 0u;
        __syncthreads();
        #pragma unroll
        for (int c = 0; c < NCH; ++c) {
            int i = c * SELT + tid;
            if (i < P) {
                int bn = (int)(__uint_as_float(lv[c]) * scale);
                if (bn > NB - 1) bn = NB - 1;
                atomicAdd(&hist[bn], 1u);
            }
        }
        __syncthreads();

        // suffix scan: suf(t) = sum of bins owned by threads > t  (4 bins/thread)
        int s4 = (int)(hist[4*tid] + hist[4*tid+1] + hist[4*tid+2] + hist[4*tid+3]);
        sums[SELT - 1 - tid] = s4;
        __syncthreads();
        int x = sums[tid];
        int xs = x;
        for (int off = 1; off < 64; off <<= 1) {
            int o = __shfl_up(xs, (unsigned)off, 64);
            if (lane >= off) xs += o;
        }
        if (lane == 63) redi[wid] = xs;
        __syncthreads();
        if (tid < 64) {
            int v = (tid < 16) ? redi[tid] : 0;
            int vs = v;
            for (int off = 1; off < 16; off <<= 1) {
                int o = __shfl_up(vs, (unsigned)off, 64);
                if (lane >= off) vs += o;
            }
            if (tid < 16) redi[tid] = vs - v;   // exclusive wave offsets
        }
        __syncthreads();
        int excl_rev = xs + redi[wid] - x;      // exclusive scan of reversed array at pos tid
        sums[tid] = excl_rev;
        __syncthreads();
        int suf = sums[SELT - 1 - tid];
        // locate K-th bin from the top within my 4 bins
        {
            int run = suf;
            for (int j = 3; j >= 0; --j) {
                int bin = 4 * tid + j;
                int h = (int)hist[bin];
                if ((long)run < K && K <= (long)run + h) { sh_b1 = bin; sh_k1 = (int)(K - run); }
                run += h;
            }
        }
        __syncthreads();
        int B1 = sh_b1, k1 = sh_k1;

        // gather candidates in bin B1
        if (tid == 0) sh_m = 0;
        __syncthreads();
        #pragma unroll
        for (int c = 0; c < NCH; ++c) {
            int i = c * SELT + tid;
            if (i < P) {
                float f = __uint_as_float(lv[c]);
                int bn = (int)(f * scale);
                if (bn > NB - 1) bn = NB - 1;
                if (bn == B1) {
                    int pos = atomicAdd(&sh_m, 1);
                    if (pos < CAP) { cv[pos] = f; ci[pos] = i; }
                }
            }
        }
        __syncthreads();
        int m = sh_m;
        if (m <= CAP) {
            // all-pairs exact rank (order-independent): find element with rank k1-1
            for (int j = tid; j < m; j += SELT) {
                float vj = cv[j]; int ij = ci[j]; int r = 0;
                for (int jj = 0; jj < m; ++jj) {
                    float vx = cv[jj];
                    r += (vx > vj || (vx == vj && ci[jj] < ij)) ? 1 : 0;
                }
                if (r == k1 - 1) { sh_T = __float_as_uint(vj); sh_istar = ij; }
            }
            __syncthreads();
            uT = sh_T; istar = sh_istar;
        } else {
            // fallback: full bit-serial radix (rare: extreme ties)
            if (tid == 0) { sh_pref = 0u; sh_kk = (int)K; }
            __syncthreads();
            for (int bit = 30; bit >= 0; --bit) {
                unsigned pref = sh_pref;
                int kk = sh_kk;
                unsigned hi = pref >> (bit + 1);
                int cnt = 0;
                #pragma unroll
                for (int c = 0; c < NCH; ++c) {
                    int i = c * SELT + tid;
                    unsigned v = lv[c];
                    cnt += ((i < P) && ((v >> (bit + 1)) == hi) && ((v >> bit) & 1u)) ? 1 : 0;
                }
                for (int off = 32; off > 0; off >>= 1) cnt += __shfl_down(cnt, (unsigned)off, 64);
                if (lane == 0) redi[wid] = cnt;
                __syncthreads();
                if (tid < 64) {
                    int v = (tid < 16) ? redi[tid] : 0;
                    for (int off = 32; off > 0; off >>= 1) v += __shfl_down(v, (unsigned)off, 64);
                    if (tid == 0) {
                        if (kk <= v) sh_pref = pref | (1u << bit);
                        else sh_kk = kk - v;
                    }
                }
                __syncthreads();
            }
            unsigned T = sh_pref; int krem = sh_kk;
            if (tid == 0) { sh_istar = -1; sh_cum = 0; }
            __syncthreads();
            for (int c = 0; c < NCH; ++c) {
                int i = c * SELT + tid;
                bool eq = (i < P) && (lv[c] == T);
                unsigned long long mk = __ballot(eq);
                if (lane == 0) redi[wid] = (int)__popcll(mk);
                __syncthreads();
                if (tid < 64) {
                    int v = (tid < 16) ? redi[tid] : 0;
                    for (int off = 1; off < 16; off <<= 1) {
                        int o = __shfl_up(v, (unsigned)off, 64);
                        if (lane >= off) v += o;
                    }
                    if (tid < 16) sh_base[tid] = v;
                }
                __syncthreads();
                int cum = sh_cum;
                int base = (wid == 0) ? 0 : sh_base[wid - 1];
                if (eq) {
                    int r = cum + base + (int)__popcll(mk & ((1ull << lane) - 1ull));
                    if (r == krem - 1) sh_istar = i;
                }
                __syncthreads();
                if (tid == 0) sh_cum = cum + sh_base[15];
                __syncthreads();
                if (sh_cum >= krem) break;
            }
            __syncthreads();
            uT = T; istar = sh_istar;
        }
    }

    // masked ce sum (fixed-order tree)
    float cs = 0.f;
    const float* ceb = ce + (size_t)b * P;
    const unsigned char* pb = posm + (size_t)b * P;
    #pragma unroll
    for (int c = 0; c < NCH; ++c) {
        int i = c * SELT + tid;
        if (i < P) {
            unsigned v = lv[c];
            bool sel = (pb[i] != 0) || (v > uT) || (v == uT && i <= istar);
            if (sel) cs += ceb[i];
        }
    }
    for (int off = 32; off > 0; off >>= 1) cs += __shfl_down(cs, (unsigned)off, 64);
    if (lane == 0) redf[wid] = cs;
    __syncthreads();
    if (tid < 64) {
        float v = (tid < 16) ? redf[tid] : 0.f;
        for (int off = 32; off > 0; off >>= 1) v += __shfl_down(v, (unsigned)off, 64);
        if (tid == 0) { partC[b] = v; npos[b] = npos_b; }
    }
}

// ---------------- final deterministic reduce + divide ----------------
__global__ void k_final(const float* __restrict__ partL, const float* __restrict__ partC,
                        const int* __restrict__ npos, int nPart,
                        float* __restrict__ out, int B) {
    __shared__ float sL[256];
    __shared__ float sC[256];
    __shared__ int   sN[256];
    int tid = threadIdx.x;
    float aL = 0.f, aC = 0.f; int aN = 0;
    for (int i = tid; i < nPart; i += 256) aL += partL[i];
    for (int i = tid; i < B; i += 256) { aC += partC[i]; aN += npos[i]; }
    sL[tid] = aL; sC[tid] = aC; sN[tid] = aN;
    __syncthreads();
    for (int off = 128; off > 0; off >>= 1) {
        if (tid < off) { sL[tid] += sL[tid+off]; sC[tid] += sC[tid+off]; sN[tid] += sN[tid+off]; }
        __syncthreads();
    }
    if (tid == 0) {
        float N = (float)sN[0];
        out[0] = sL[0] / N;
        out[1] = sC[0] / N;
    }
}

extern "C" void kernel_launch(void* const* d_in, const int* in_sizes, int n_in,
                              void* d_out, int out_size, void* d_ws, size_t ws_size,
                              hipStream_t stream) {
    const float* arm_loc  = (const float*)d_in[0];
    const float* arm_conf = (const float*)d_in[1];
    const float* odm_loc  = (const float*)d_in[2];
    const float* odm_conf = (const float*)d_in[3];
    const float* priors   = (const float*)d_in[4];
    const float* targets  = (const float*)d_in[5];
    const int*   num_gts  = (const int*)d_in[6];
    float* out = (float*)d_out;

    int B = in_sizes[6];
    int P = in_sizes[4] / 4;
    int C = in_sizes[3] / (B * P);
    int G = in_sizes[5] / (B * 5);
    int NBX = (P + BLK - 1) / BLK;

    char* ws = (char*)d_ws;
    size_t off = 0;
    auto alloc = [&](size_t bytes) -> void* {
        void* ptr = ws + off;
        off = (off + bytes + 255) & ~(size_t)255;
        return ptr;
    };
    unsigned long long* bp = (unsigned long long*)alloc((size_t)B * G * 8);  // memset 0
    size_t zero_bytes = off;
    float* dec = (float*)alloc((size_t)B * P * 4 * sizeof(float));
    unsigned long long* bt = (unsigned long long*)alloc((size_t)B * P * 8);
    float* lc  = (float*)alloc((size_t)B * P * sizeof(float));
    float* ce  = (float*)alloc((size_t)B * P * sizeof(float));
    unsigned char* posm = (unsigned char*)alloc((size_t)B * P);
    float* partL = (float*)alloc((size_t)B * NBX * sizeof(float));
    int* partN   = (int*)alloc((size_t)B * NBX * sizeof(int));
    float* partC = (float*)alloc((size_t)B * sizeof(float));
    int* npos    = (int*)alloc((size_t)B * sizeof(int));

    hipMemsetAsync(ws, 0, zero_bytes, stream);

    k_iou<<<dim3(NBX, B), BLK, 0, stream>>>(arm_loc, priors, targets, num_gts, dec, bt, bp, B, P, G);
    k_fix<<<B, 64, 0, stream>>>(num_gts, bp, bt, B, P, G);
    k_main<<<dim3(NBX, B), BLK, 0, stream>>>(dec, arm_conf, odm_loc, odm_conf, targets,
                                             bt, lc, ce, posm, partL, partN, B, P, C, G);
    k_select<<<B, SELT, 0, stream>>>(lc, ce, posm, partN, NBX, partC, npos, P);
    k_final<<<1, 256, 0, stream>>>(partL, partC, npos, B * NBX, out, B);
}

// Round 5
// 79.796 us; speedup vs baseline: 4.0608x; 1.5567x over previous
//
#include <hip/hip_runtime.h>
#include <math.h>

#define VAR0 0.1f
#define VAR1 0.2f
#define THRESH 0.5f
#define THETA 0.01f
#define MAXG 64
#define BLK 256
#define SELT 1024
#define NCH 16     // ceil(P/SELT) for P=16320
#define NB 4096    // histogram bins
#define CAP 2048   // candidate buffer

// wave-wide max of non-negative float bit patterns via DPP (VALU-only, result in all lanes via readlane)
__device__ __forceinline__ unsigned wave_umax_bits(unsigned v) {
    int x = (int)v;
    int t;
    t = __builtin_amdgcn_update_dpp(0, x, 0x111, 0xf, 0xf, true);  x = (t > x) ? t : x; // row_shr:1
    t = __builtin_amdgcn_update_dpp(0, x, 0x112, 0xf, 0xf, true);  x = (t > x) ? t : x; // row_shr:2
    t = __builtin_amdgcn_update_dpp(0, x, 0x114, 0xf, 0xf, true);  x = (t > x) ? t : x; // row_shr:4
    t = __builtin_amdgcn_update_dpp(0, x, 0x118, 0xf, 0xf, true);  x = (t > x) ? t : x; // row_shr:8
    t = __builtin_amdgcn_update_dpp(0, x, 0x142, 0xa, 0xf, false); x = (t > x) ? t : x; // row_bcast:15
    t = __builtin_amdgcn_update_dpp(0, x, 0x143, 0xc, 0xf, false); x = (t > x) ? t : x; // row_bcast:31
    return (unsigned)__builtin_amdgcn_readlane(x, 63);
}

// ---------------- fused decode + per-p best-over-g + per-(g,wave) winner to scratch ----------------
__global__ void k_iou(const float* __restrict__ arm_loc, const float* __restrict__ priors,
                      const float* __restrict__ targets, const int* __restrict__ num_gts,
                      float* __restrict__ dec, unsigned long long* __restrict__ bt,
                      unsigned long long* __restrict__ bpw,
                      int B, int P, int G, int W) {
    int b = blockIdx.y;
    int p = blockIdx.x * blockDim.x + threadIdx.x;
    int tid = threadIdx.x;
    int lane = tid & 63;
    int wv_id = blockIdx.x * (blockDim.x >> 6) + (tid >> 6);
    int wavebase = blockIdx.x * (int)blockDim.x + (tid & ~63);
    __shared__ float st[MAXG * 5];
    __shared__ int sng;
    if (tid == 0) sng = num_gts[b];
    for (int i = tid; i < G * 5; i += blockDim.x) st[i] = targets[(size_t)b * G * 5 + i];
    __syncthreads();
    int ng = sng;
    bool ok = p < P;
    float4 d = make_float4(0.f, 0.f, 0.f, 0.f);
    float areaB = 0.f;
    size_t i = (size_t)b * P + (ok ? p : 0);
    if (ok) {
        float4 l = ((const float4*)arm_loc)[i];
        float4 pr = ((const float4*)priors)[p];
        float cx = pr.x + l.x * VAR0 * pr.z;
        float cy = pr.y + l.y * VAR0 * pr.w;
        float w = pr.z * expf(l.z * VAR1);
        float h = pr.w * expf(l.w * VAR1);
        d.x = cx - w * 0.5f; d.y = cy - h * 0.5f;
        d.z = cx + w * 0.5f; d.w = cy + h * 0.5f;
        ((float4*)dec)[i] = d;
        areaB = (d.z - d.x) * (d.w - d.y);
    }
    float bov = -2.0f; int bidx = 0;
    for (int g = 0; g < ng; ++g) {
        float t0 = st[g*5], t1 = st[g*5+1], t2 = st[g*5+2], t3 = st[g*5+3];
        unsigned vbits = 0u;
        if (ok) {
            float lt0 = fmaxf(t0, d.x), lt1 = fmaxf(t1, d.y);
            float rb0 = fminf(t2, d.z), rb1 = fminf(t3, d.w);
            float w = rb0 - lt0; if (w < 0.f) w = 0.f;
            float h = rb1 - lt1; if (h < 0.f) h = 0.f;
            float inter = w * h;
            float areaA = (t2 - t0) * (t3 - t1);
            float ov = inter / (areaA + areaB - inter);
            if (ov > bov) { bov = ov; bidx = g; }   // first occurrence of max over g
            vbits = __float_as_uint(ov);            // ov >= 0 -> bits order-preserving
        }
        unsigned om = wave_umax_bits(vbits);
        unsigned long long mask = __ballot(vbits == om);   // lowest set bit = smallest p
        if (lane == 0) {
            int p_win = wavebase + (int)__builtin_ctzll(mask);
            bpw[(size_t)(b * G + g) * W + wv_id] =
                ((unsigned long long)om << 32)
                | (unsigned long long)(0xFFFFFFFFu - (unsigned)p_win);
        }
    }
    if (ok)
        bt[i] = ((unsigned long long)__float_as_uint(bov) << 32) | (unsigned)bidx;
}

// ---------------- reduce per-wave winners; forced matches (max-g = last-wins) ----------------
__global__ void k_fix(const int* __restrict__ num_gts, const unsigned long long* __restrict__ bpw,
                      unsigned long long* __restrict__ bt, int B, int P, int G, int W) {
    int b = blockIdx.x;
    int tid = threadIdx.x;
    int lane = tid & 63, wid = tid >> 6;
    __shared__ int fp[MAXG];
    __shared__ int sng;
    if (tid == 0) sng = num_gts[b];
    __syncthreads();
    int ng = sng;
    for (int g = wid; g < ng; g += 4) {
        const unsigned long long* src = bpw + (size_t)(b * G + g) * W;
        unsigned long long key = 0ull;
        for (int j = lane; j < W; j += 64) {
            unsigned long long v = src[j];
            if (v > key) key = v;
        }
        for (int off = 32; off > 0; off >>= 1) {
            unsigned long long o = __shfl_down(key, (unsigned)off, 64);
            if (o > key) key = o;
        }
        if (lane == 0) fp[g] = (int)(0xFFFFFFFFu - (unsigned)(key & 0xFFFFFFFFull));
    }
    __syncthreads();
    for (int g = tid; g < ng; g += blockDim.x) {
        unsigned long long fkey = ((unsigned long long)0x40000000u << 32) | (unsigned)g; // 2.0f hi
        atomicMax(&bt[(size_t)b * P + fp[g]], fkey);
    }
}

// ---------------- main pass: pos/smoothL1/lse/ce/lc (odm_conf LDS-staged) ----------------
__global__ void k_main(const float* __restrict__ dec, const float* __restrict__ arm_conf,
                       const float* __restrict__ odm_loc, const float* __restrict__ odm_conf,
                       const float* __restrict__ targets,
                       const unsigned long long* __restrict__ bt,
                       float* __restrict__ lc, float* __restrict__ ce,
                       unsigned char* __restrict__ posm,
                       float* __restrict__ partL, int* __restrict__ partN,
                       int B, int P, int C, int G) {
    int b = blockIdx.y;
    int p0 = blockIdx.x * BLK;
    int tid = threadIdx.x;
    int p = p0 + tid;
    __shared__ float st[MAXG * 5];
    __shared__ float oc_s[BLK * 21];   // assumes C == 21
    for (int i2 = tid; i2 < G * 5; i2 += BLK) st[i2] = targets[(size_t)b * G * 5 + i2];
    int nrows = P - p0; if (nrows > BLK) nrows = BLK;
    int nf = nrows * C;
    const float* ocb = odm_conf + ((size_t)b * P + p0) * C;
    int nf4 = nf >> 2;
    const float4* ocb4 = (const float4*)ocb;
    for (int i2 = tid; i2 < nf4; i2 += BLK) ((float4*)oc_s)[i2] = ocb4[i2];
    if (tid < (nf & 3)) oc_s[(nf4 << 2) + tid] = ocb[(nf4 << 2) + tid];
    __syncthreads();
    float lsum = 0.f; int pc = 0;
    if (p < P) {
        size_t i = (size_t)b * P + p;
        unsigned long long mv = bt[i];
        float bov = __uint_as_float((unsigned)(mv >> 32));
        int bidx = (int)(mv & 0xFFFFFFFFull);
        int conf_t = (bov < THRESH) ? 0 : (int)st[bidx*5+4];
        float2 c = ((const float2*)arm_conf)[i];
        float mm = fmaxf(c.x, c.y);
        float e0 = expf(c.x - mm), e1 = expf(c.y - mm);
        float p_obj = e1 / (e0 + e1);
        bool pos = (conf_t > 0) && (p_obj > THETA);
        if (pos) {
            pc = 1;
            float4 d = ((const float4*)dec)[i];
            float pcx = (d.x + d.z) * 0.5f, pcy = (d.y + d.w) * 0.5f;
            float pw = d.z - d.x, ph = d.w - d.y;
            float t0 = st[bidx*5], t1 = st[bidx*5+1], t2 = st[bidx*5+2], t3 = st[bidx*5+3];
            float g0 = ((t0 + t2) * 0.5f - pcx) / (VAR0 * pw);
            float g1 = ((t1 + t3) * 0.5f - pcy) / (VAR0 * ph);
            float g2 = logf((t2 - t0) / pw) / VAR1;
            float g3 = logf((t3 - t1) / ph) / VAR1;
            float4 ol = ((const float4*)odm_loc)[i];
            float dd;
            dd = fabsf(ol.x - g0); lsum += (dd < 1.f) ? 0.5f*dd*dd : dd - 0.5f;
            dd = fabsf(ol.y - g1); lsum += (dd < 1.f) ? 0.5f*dd*dd : dd - 0.5f;
            dd = fabsf(ol.z - g2); lsum += (dd < 1.f) ? 0.5f*dd*dd : dd - 0.5f;
            dd = fabsf(ol.w - g3); lsum += (dd < 1.f) ? 0.5f*dd*dd : dd - 0.5f;
        }
        const float* oc = oc_s + tid * C;
        float mx = oc[0];
        for (int j = 1; j < C; ++j) mx = fmaxf(mx, oc[j]);
        float sume = 0.f;
        for (int j = 0; j < C; ++j) sume += expf(oc[j] - mx);
        float lse = mx + logf(sume);
        float cev = lse - oc[conf_t];
        ce[i] = cev;
        lc[i] = pos ? 0.f : cev;
        posm[i] = pos ? 1 : 0;
    }
    __shared__ float rl[BLK];
    __shared__ int rc[BLK];
    rl[tid] = lsum; rc[tid] = pc;
    __syncthreads();
    for (int off = BLK/2; off > 0; off >>= 1) {
        if (tid < off) { rl[tid] += rl[tid+off]; rc[tid] += rc[tid+off]; }
        __syncthreads();
    }
    if (tid == 0) {
        partL[b * gridDim.x + blockIdx.x] = rl[0];
        partN[b * gridDim.x + blockIdx.x] = rc[0];
    }
}

// ---------------- per-batch: histogram-select Kth-largest + tie-break + masked ce sum ----------------
__global__ __launch_bounds__(SELT) void k_select(
        const float* __restrict__ lc, const float* __restrict__ ce,
        const unsigned char* __restrict__ posm,
        const int* __restrict__ partN, int NBX,
        float* __restrict__ partC, int* __restrict__ npos, int P) {
    int b = blockIdx.x;
    int tid = threadIdx.x;
    int lane = tid & 63, wid = tid >> 6;
    __shared__ unsigned hist[NB];
    __shared__ float cv[CAP];
    __shared__ int   ci[CAP];
    __shared__ int   sums[SELT];
    __shared__ int   redi[16];
    __shared__ float redf[16];
    __shared__ int sh_base[16];
    __shared__ int sh_m, sh_b1, sh_k1, sh_npos, sh_istar, sh_kk, sh_cum;
    __shared__ unsigned sh_T, sh_pref;
    __shared__ float sh_mx;

    // npos_b from per-block partials (deterministic)
    int c0 = 0;
    for (int j = tid; j < NBX; j += SELT) c0 += partN[b * NBX + j];
    for (int off = 32; off > 0; off >>= 1) c0 += __shfl_down(c0, (unsigned)off, 64);
    if (lane == 0) redi[wid] = c0;
    __syncthreads();
    if (tid < 64) {
        int v = (tid < 16) ? redi[tid] : 0;
        for (int off = 32; off > 0; off >>= 1) v += __shfl_down(v, (unsigned)off, 64);
        if (tid == 0) sh_npos = v;
    }
    __syncthreads();
    int npos_b = sh_npos;
    long K = 3L * npos_b;
    if (K > P - 1) K = P - 1;

    // register-resident lc bit patterns
    unsigned lv[NCH];
    const unsigned* lcb = (const unsigned*)lc + (size_t)b * P;
    #pragma unroll
    for (int c = 0; c < NCH; ++c) {
        int i = c * SELT + tid;
        lv[c] = (i < P) ? lcb[i] : 0u;
    }

    unsigned uT = 0xFFFFFFFFu; int istar = -1;
    if (K > 0) {
        // batch max
        float mx = 0.f;
        #pragma unroll
        for (int c = 0; c < NCH; ++c) mx = fmaxf(mx, __uint_as_float(lv[c]));
        for (int off = 32; off > 0; off >>= 1) mx = fmaxf(mx, __shfl_xor(mx, off, 64));
        if (lane == 0) redf[wid] = mx;
        __syncthreads();
        if (tid == 0) {
            float v = redf[0];
            for (int w = 1; w < 16; ++w) v = fmaxf(v, redf[w]);
            sh_mx = v;
        }
        __syncthreads();
        float vmax = sh_mx;
        float scale = (vmax > 0.f) ? ((float)NB / vmax) : 0.f;

        // histogram (linear bins -> near-uniform, low contention)
        for (int j = tid; j < NB; j += SELT) hist[j] = 0u;
        __syncthreads();
        #pragma unroll
        for (int c = 0; c < NCH; ++c) {
            int i = c * SELT + tid;
            if (i < P) {
                int bn = (int)(__uint_as_float(lv[c]) * scale);
                if (bn > NB - 1) bn = NB - 1;
                atomicAdd(&hist[bn], 1u);
            }
        }
        __syncthreads();

        // suffix scan: suf(t) = sum of bins owned by threads > t  (4 bins/thread)
        int s4 = (int)(hist[4*tid] + hist[4*tid+1] + hist[4*tid+2] + hist[4*tid+3]);
        sums[SELT - 1 - tid] = s4;
        __syncthreads();
        int x = sums[tid];
        int xs = x;
        for (int off = 1; off < 64; off <<= 1) {
            int o = __shfl_up(xs, (unsigned)off, 64);
            if (lane >= off) xs += o;
        }
        if (lane == 63) redi[wid] = xs;
        __syncthreads();
        if (tid < 64) {
            int v = (tid < 16) ? redi[tid] : 0;
            int vs = v;
            for (int off = 1; off < 16; off <<= 1) {
                int o = __shfl_up(vs, (unsigned)off, 64);
                if (lane >= off) vs += o;
            }
            if (tid < 16) redi[tid] = vs - v;   // exclusive wave offsets
        }
        __syncthreads();
        int excl_rev = xs + redi[wid] - x;      // exclusive scan of reversed array at pos tid
        sums[tid] = excl_rev;
        __syncthreads();
        int suf = sums[SELT - 1 - tid];
        // locate K-th bin from the top within my 4 bins
        {
            int run = suf;
            for (int j = 3; j >= 0; --j) {
                int bin = 4 * tid + j;
                int h = (int)hist[bin];
                if ((long)run < K && K <= (long)run + h) { sh_b1 = bin; sh_k1 = (int)(K - run); }
                run += h;
            }
        }
        __syncthreads();
        int B1 = sh_b1, k1 = sh_k1;

        // gather candidates in bin B1
        if (tid == 0) sh_m = 0;
        __syncthreads();
        #pragma unroll
        for (int c = 0; c < NCH; ++c) {
            int i = c * SELT + tid;
            if (i < P) {
                float f = __uint_as_float(lv[c]);
                int bn = (int)(f * scale);
                if (bn > NB - 1) bn = NB - 1;
                if (bn == B1) {
                    int pos = atomicAdd(&sh_m, 1);
                    if (pos < CAP) { cv[pos] = f; ci[pos] = i; }
                }
            }
        }
        __syncthreads();
        int m = sh_m;
        if (m <= CAP) {
            // all-pairs exact rank (order-independent): find element with rank k1-1
            for (int j = tid; j < m; j += SELT) {
                float vj = cv[j]; int ij = ci[j]; int r = 0;
                for (int jj = 0; jj < m; ++jj) {
                    float vx = cv[jj];
                    r += (vx > vj || (vx == vj && ci[jj] < ij)) ? 1 : 0;
                }
                if (r == k1 - 1) { sh_T = __float_as_uint(vj); sh_istar = ij; }
            }
            __syncthreads();
            uT = sh_T; istar = sh_istar;
        } else {
            // fallback: full bit-serial radix (rare: extreme ties)
            if (tid == 0) { sh_pref = 0u; sh_kk = (int)K; }
            __syncthreads();
            for (int bit = 30; bit >= 0; --bit) {
                unsigned pref = sh_pref;
                int kk = sh_kk;
                unsigned hi = pref >> (bit + 1);
                int cnt = 0;
                #pragma unroll
                for (int c = 0; c < NCH; ++c) {
                    int i = c * SELT + tid;
                    unsigned v = lv[c];
                    cnt += ((i < P) && ((v >> (bit + 1)) == hi) && ((v >> bit) & 1u)) ? 1 : 0;
                }
                for (int off = 32; off > 0; off >>= 1) cnt += __shfl_down(cnt, (unsigned)off, 64);
                if (lane == 0) redi[wid] = cnt;
                __syncthreads();
                if (tid < 64) {
                    int v = (tid < 16) ? redi[tid] : 0;
                    for (int off = 32; off > 0; off >>= 1) v += __shfl_down(v, (unsigned)off, 64);
                    if (tid == 0) {
                        if (kk <= v) sh_pref = pref | (1u << bit);
                        else sh_kk = kk - v;
                    }
                }
                __syncthreads();
            }
            unsigned T = sh_pref; int krem = sh_kk;
            if (tid == 0) { sh_istar = -1; sh_cum = 0; }
            __syncthreads();
            for (int c = 0; c < NCH; ++c) {
                int i = c * SELT + tid;
                bool eq = (i < P) && (lv[c] == T);
                unsigned long long mk = __ballot(eq);
                if (lane == 0) redi[wid] = (int)__popcll(mk);
                __syncthreads();
                if (tid < 64) {
                    int v = (tid < 16) ? redi[tid] : 0;
                    for (int off = 1; off < 16; off <<= 1) {
                        int o = __shfl_up(v, (unsigned)off, 64);
                        if (lane >= off) v += o;
                    }
                    if (tid < 16) sh_base[tid] = v;
                }
                __syncthreads();
                int cum = sh_cum;
                int base = (wid == 0) ? 0 : sh_base[wid - 1];
                if (eq) {
                    int r = cum + base + (int)__popcll(mk & ((1ull << lane) - 1ull));
                    if (r == krem - 1) sh_istar = i;
                }
                __syncthreads();
                if (tid == 0) sh_cum = cum + sh_base[15];
                __syncthreads();
                if (sh_cum >= krem) break;
            }
            __syncthreads();
            uT = T; istar = sh_istar;
        }
    }

    // masked ce sum (fixed-order tree)
    float cs = 0.f;
    const float* ceb = ce + (size_t)b * P;
    const unsigned char* pb = posm + (size_t)b * P;
    #pragma unroll
    for (int c = 0; c < NCH; ++c) {
        int i = c * SELT + tid;
        if (i < P) {
            unsigned v = lv[c];
            bool sel = (pb[i] != 0) || (v > uT) || (v == uT && i <= istar);
            if (sel) cs += ceb[i];
        }
    }
    for (int off = 32; off > 0; off >>= 1) cs += __shfl_down(cs, (unsigned)off, 64);
    if (lane == 0) redf[wid] = cs;
    __syncthreads();
    if (tid < 64) {
        float v = (tid < 16) ? redf[tid] : 0.f;
        for (int off = 32; off > 0; off >>= 1) v += __shfl_down(v, (unsigned)off, 64);
        if (tid == 0) { partC[b] = v; npos[b] = npos_b; }
    }
}

// ---------------- final deterministic reduce + divide ----------------
__global__ void k_final(const float* __restrict__ partL, const float* __restrict__ partC,
                        const int* __restrict__ npos, int nPart,
                        float* __restrict__ out, int B) {
    __shared__ float sL[256];
    __shared__ float sC[256];
    __shared__ int   sN[256];
    int tid = threadIdx.x;
    float aL = 0.f, aC = 0.f; int aN = 0;
    for (int i = tid; i < nPart; i += 256) aL += partL[i];
    for (int i = tid; i < B; i += 256) { aC += partC[i]; aN += npos[i]; }
    sL[tid] = aL; sC[tid] = aC; sN[tid] = aN;
    __syncthreads();
    for (int off = 128; off > 0; off >>= 1) {
        if (tid < off) { sL[tid] += sL[tid+off]; sC[tid] += sC[tid+off]; sN[tid] += sN[tid+off]; }
        __syncthreads();
    }
    if (tid == 0) {
        float N = (float)sN[0];
        out[0] = sL[0] / N;
        out[1] = sC[0] / N;
    }
}

extern "C" void kernel_launch(void* const* d_in, const int* in_sizes, int n_in,
                              void* d_out, int out_size, void* d_ws, size_t ws_size,
                              hipStream_t stream) {
    const float* arm_loc  = (const float*)d_in[0];
    const float* arm_conf = (const float*)d_in[1];
    const float* odm_loc  = (const float*)d_in[2];
    const float* odm_conf = (const float*)d_in[3];
    const float* priors   = (const float*)d_in[4];
    const float* targets  = (const float*)d_in[5];
    const int*   num_gts  = (const int*)d_in[6];
    float* out = (float*)d_out;

    int B = in_sizes[6];
    int P = in_sizes[4] / 4;
    int C = in_sizes[3] / (B * P);
    int G = in_sizes[5] / (B * 5);
    int NBX = (P + BLK - 1) / BLK;
    int W = NBX * (BLK / 64);   // per-wave winner slots per (b,g)

    char* ws = (char*)d_ws;
    size_t off = 0;
    auto alloc = [&](size_t bytes) -> void* {
        void* ptr = ws + off;
        off = (off + bytes + 255) & ~(size_t)255;
        return ptr;
    };
    float* dec = (float*)alloc((size_t)B * P * 4 * sizeof(float));
    unsigned long long* bt = (unsigned long long*)alloc((size_t)B * P * 8);
    unsigned long long* bpw = (unsigned long long*)alloc((size_t)B * G * W * 8);
    float* lc  = (float*)alloc((size_t)B * P * sizeof(float));
    float* ce  = (float*)alloc((size_t)B * P * sizeof(float));
    unsigned char* posm = (unsigned char*)alloc((size_t)B * P);
    float* partL = (float*)alloc((size_t)B * NBX * sizeof(float));
    int* partN   = (int*)alloc((size_t)B * NBX * sizeof(int));
    float* partC = (float*)alloc((size_t)B * sizeof(float));
    int* npos    = (int*)alloc((size_t)B * sizeof(int));

    k_iou<<<dim3(NBX, B), BLK, 0, stream>>>(arm_loc, priors, targets, num_gts, dec, bt, bpw, B, P, G, W);
    k_fix<<<B, BLK, 0, stream>>>(num_gts, bpw, bt, B, P, G, W);
    k_main<<<dim3(NBX, B), BLK, 0, stream>>>(dec, arm_conf, odm_loc, odm_conf, targets,
                                             bt, lc, ce, posm, partL, partN, B, P, C, G);
    k_select<<<B, SELT, 0, stream>>>(lc, ce, posm, partN, NBX, partC, npos, P);
    k_final<<<1, 256, 0, stream>>>(partL, partC, npos, B * NBX, out, B);
}

// Round 6
// 64.119 us; speedup vs baseline: 5.0537x; 1.2445x over previous
//
#include <hip/hip_runtime.h>
#include <math.h>

#define VAR0 0.1f
#define VAR1 0.2f
#define THRESH 0.5f
#define THETA 0.01f
#define MAXG 64
#define BLK 256
#define SELT 1024
#define NCH 16     // ceil(P/SELT) for P=16320
#define NB 4096    // histogram bins
#define CAP 2048   // candidate buffer

// shared decode (identical codegen in k_iou and k_main)
__device__ __forceinline__ float4 decode_box(float4 l, float4 pr) {
    float cx = pr.x + l.x * VAR0 * pr.z;
    float cy = pr.y + l.y * VAR0 * pr.w;
    float w = pr.z * expf(l.z * VAR1);
    float h = pr.w * expf(l.w * VAR1);
    return make_float4(cx - w * 0.5f, cy - h * 0.5f, cx + w * 0.5f, cy + h * 0.5f);
}

// wave-wide max of non-negative float bit patterns via DPP (VALU-only)
__device__ __forceinline__ unsigned wave_umax_bits(unsigned v) {
    int x = (int)v;
    int t;
    t = __builtin_amdgcn_update_dpp(0, x, 0x111, 0xf, 0xf, true);  x = (t > x) ? t : x; // row_shr:1
    t = __builtin_amdgcn_update_dpp(0, x, 0x112, 0xf, 0xf, true);  x = (t > x) ? t : x; // row_shr:2
    t = __builtin_amdgcn_update_dpp(0, x, 0x114, 0xf, 0xf, true);  x = (t > x) ? t : x; // row_shr:4
    t = __builtin_amdgcn_update_dpp(0, x, 0x118, 0xf, 0xf, true);  x = (t > x) ? t : x; // row_shr:8
    t = __builtin_amdgcn_update_dpp(0, x, 0x142, 0xa, 0xf, false); x = (t > x) ? t : x; // row_bcast:15
    t = __builtin_amdgcn_update_dpp(0, x, 0x143, 0xc, 0xf, false); x = (t > x) ? t : x; // row_bcast:31
    return (unsigned)__builtin_amdgcn_readlane(x, 63);
}

// ---------------- fused decode + per-p best-over-g + per-(g,block) winner to scratch ----------------
__global__ void k_iou(const float* __restrict__ arm_loc, const float* __restrict__ priors,
                      const float* __restrict__ targets, const int* __restrict__ num_gts,
                      unsigned long long* __restrict__ bt,
                      unsigned long long* __restrict__ bpw,
                      int B, int P, int G) {
    int b = blockIdx.y;
    int p = blockIdx.x * blockDim.x + threadIdx.x;
    int tid = threadIdx.x;
    int lane = tid & 63, wid = tid >> 6;
    int wavebase = blockIdx.x * (int)blockDim.x + (tid & ~63);
    __shared__ float4 st4[MAXG];
    __shared__ float  stl[MAXG];
    __shared__ unsigned long long wk[4][MAXG];
    __shared__ int sng;
    if (tid == 0) sng = num_gts[b];
    for (int i = tid; i < G * 4; i += blockDim.x) {
        int g = i >> 2, k = i & 3;
        ((float*)&st4[g])[k] = targets[(size_t)b * G * 5 + g * 5 + k];
    }
    for (int g = tid; g < G; g += blockDim.x) stl[g] = targets[(size_t)b * G * 5 + g * 5 + 4];
    __syncthreads();
    int ng = sng;
    bool ok = p < P;
    float4 d = make_float4(0.f, 0.f, 0.f, 0.f);
    float areaB = 0.f;
    size_t i = (size_t)b * P + (ok ? p : 0);
    if (ok) {
        float4 l = ((const float4*)arm_loc)[i];
        float4 pr = ((const float4*)priors)[p];
        d = decode_box(l, pr);
        areaB = (d.z - d.x) * (d.w - d.y);
    }
    float bov = -2.0f; int bidx = 0;
    for (int g = 0; g < ng; ++g) {
        float4 t = st4[g];
        unsigned vbits = 0u;
        if (ok) {
            float lt0 = fmaxf(t.x, d.x), lt1 = fmaxf(t.y, d.y);
            float rb0 = fminf(t.z, d.z), rb1 = fminf(t.w, d.w);
            float w = rb0 - lt0; if (w < 0.f) w = 0.f;
            float h = rb1 - lt1; if (h < 0.f) h = 0.f;
            float inter = w * h;
            float areaA = (t.z - t.x) * (t.w - t.y);
            float ov = inter / (areaA + areaB - inter);
            if (ov > bov) { bov = ov; bidx = g; }   // first occurrence of max over g
            vbits = __float_as_uint(ov);            // ov >= 0 -> bits order-preserving
        }
        unsigned om = wave_umax_bits(vbits);
        unsigned long long mask = __ballot(vbits == om);   // lowest set bit = smallest p
        if (lane == 0) {
            int p_win = wavebase + (int)__builtin_ctzll(mask);
            wk[wid][g] = ((unsigned long long)om << 32)
                       | (unsigned long long)(0xFFFFFFFFu - (unsigned)p_win);
        }
    }
    if (ok)
        bt[i] = ((unsigned long long)__float_as_uint(bov) << 32) | (unsigned)bidx;
    __syncthreads();
    if (tid < ng) {
        unsigned long long k0 = wk[0][tid], k1 = wk[1][tid];
        unsigned long long k2 = wk[2][tid], k3 = wk[3][tid];
        unsigned long long m01 = k0 > k1 ? k0 : k1;
        unsigned long long m23 = k2 > k3 ? k2 : k3;
        unsigned long long m = m01 > m23 ? m01 : m23;
        bpw[(size_t)(b * G + tid) * gridDim.x + blockIdx.x] = m;
    }
}

// ---------------- per-(b,g): reduce block winners; forced match (max-g = last-wins) ----------------
__global__ void k_fix(const int* __restrict__ num_gts, const unsigned long long* __restrict__ bpw,
                      unsigned long long* __restrict__ bt, int B, int P, int G, int NBX) {
    int g = blockIdx.x, b = blockIdx.y;
    int lane = threadIdx.x;   // 64 threads
    if (g >= num_gts[b]) return;
    const unsigned long long* src = bpw + (size_t)(b * G + g) * NBX;
    unsigned long long key = 0ull;
    for (int j = lane; j < NBX; j += 64) {
        unsigned long long v = src[j];
        if (v > key) key = v;
    }
    for (int off = 32; off > 0; off >>= 1) {
        unsigned long long o = __shfl_down(key, (unsigned)off, 64);
        if (o > key) key = o;
    }
    if (lane == 0) {
        unsigned p = 0xFFFFFFFFu - (unsigned)(key & 0xFFFFFFFFull);
        unsigned long long fkey = ((unsigned long long)0x40000000u << 32) | (unsigned)g; // 2.0f hi
        atomicMax(&bt[(size_t)b * P + p], fkey);
    }
}

// ---------------- main pass: pos/smoothL1/lse/ce (odm_conf LDS-staged; decode recomputed) ----------------
__global__ void k_main(const float* __restrict__ arm_loc, const float* __restrict__ priors,
                       const float* __restrict__ arm_conf,
                       const float* __restrict__ odm_loc, const float* __restrict__ odm_conf,
                       const float* __restrict__ targets,
                       const unsigned long long* __restrict__ bt,
                       float* __restrict__ ce, unsigned char* __restrict__ posm,
                       float* __restrict__ partL, int* __restrict__ partN,
                       int B, int P, int C, int G) {
    int b = blockIdx.y;
    int p0 = blockIdx.x * BLK;
    int tid = threadIdx.x;
    int p = p0 + tid;
    __shared__ float4 st4[MAXG];
    __shared__ float  stl[MAXG];
    __shared__ float oc_s[BLK * 21];   // assumes C == 21
    for (int i2 = tid; i2 < G * 4; i2 += BLK) {
        int g = i2 >> 2, k = i2 & 3;
        ((float*)&st4[g])[k] = targets[(size_t)b * G * 5 + g * 5 + k];
    }
    for (int g = tid; g < G; g += BLK) stl[g] = targets[(size_t)b * G * 5 + g * 5 + 4];
    int nrows = P - p0; if (nrows > BLK) nrows = BLK;
    int nf = nrows * C;
    const float* ocb = odm_conf + ((size_t)b * P + p0) * C;
    int nf4 = nf >> 2;
    const float4* ocb4 = (const float4*)ocb;
    for (int i2 = tid; i2 < nf4; i2 += BLK) ((float4*)oc_s)[i2] = ocb4[i2];
    if (tid < (nf & 3)) oc_s[(nf4 << 2) + tid] = ocb[(nf4 << 2) + tid];
    __syncthreads();
    float lsum = 0.f; int pc = 0;
    if (p < P) {
        size_t i = (size_t)b * P + p;
        unsigned long long mv = bt[i];
        float bov = __uint_as_float((unsigned)(mv >> 32));
        int bidx = (int)(mv & 0xFFFFFFFFull);
        int conf_t = (bov < THRESH) ? 0 : (int)stl[bidx];
        float2 c = ((const float2*)arm_conf)[i];
        float mm = fmaxf(c.x, c.y);
        float e0 = expf(c.x - mm), e1 = expf(c.y - mm);
        float p_obj = e1 / (e0 + e1);
        bool pos = (conf_t > 0) && (p_obj > THETA);
        if (pos) {
            pc = 1;
            float4 l = ((const float4*)arm_loc)[i];
            float4 pr = ((const float4*)priors)[p];
            float4 d = decode_box(l, pr);
            float pcx = (d.x + d.z) * 0.5f, pcy = (d.y + d.w) * 0.5f;
            float pw = d.z - d.x, ph = d.w - d.y;
            float4 t = st4[bidx];
            float g0 = ((t.x + t.z) * 0.5f - pcx) / (VAR0 * pw);
            float g1 = ((t.y + t.w) * 0.5f - pcy) / (VAR0 * ph);
            float g2 = logf((t.z - t.x) / pw) / VAR1;
            float g3 = logf((t.w - t.y) / ph) / VAR1;
            float4 ol = ((const float4*)odm_loc)[i];
            float dd;
            dd = fabsf(ol.x - g0); lsum += (dd < 1.f) ? 0.5f*dd*dd : dd - 0.5f;
            dd = fabsf(ol.y - g1); lsum += (dd < 1.f) ? 0.5f*dd*dd : dd - 0.5f;
            dd = fabsf(ol.z - g2); lsum += (dd < 1.f) ? 0.5f*dd*dd : dd - 0.5f;
            dd = fabsf(ol.w - g3); lsum += (dd < 1.f) ? 0.5f*dd*dd : dd - 0.5f;
        }
        const float* oc = oc_s + tid * C;
        float mx = oc[0];
        for (int j = 1; j < C; ++j) mx = fmaxf(mx, oc[j]);
        float sume = 0.f;
        for (int j = 0; j < C; ++j) sume += expf(oc[j] - mx);
        float lse = mx + logf(sume);
        float cev = lse - oc[conf_t];
        ce[i] = cev;
        posm[i] = pos ? 1 : 0;
    }
    __shared__ float rl[BLK];
    __shared__ int rc[BLK];
    rl[tid] = lsum; rc[tid] = pc;
    __syncthreads();
    for (int off = BLK/2; off > 0; off >>= 1) {
        if (tid < off) { rl[tid] += rl[tid+off]; rc[tid] += rc[tid+off]; }
        __syncthreads();
    }
    if (tid == 0) {
        partL[b * gridDim.x + blockIdx.x] = rl[0];
        partN[b * gridDim.x + blockIdx.x] = rc[0];
    }
}

// ---------------- per-batch: histogram-select Kth-largest + tie-break + masked ce sum ----------------
__global__ __launch_bounds__(SELT) void k_select(
        const float* __restrict__ ce, const unsigned char* __restrict__ posm,
        const int* __restrict__ partN, int NBX,
        float* __restrict__ partC, int* __restrict__ npos, int P) {
    int b = blockIdx.x;
    int tid = threadIdx.x;
    int lane = tid & 63, wid = tid >> 6;
    __shared__ unsigned hist[NB];
    __shared__ float cv[CAP];
    __shared__ int   ci[CAP];
    __shared__ int   sums[SELT];
    __shared__ int   redi[16];
    __shared__ float redf[16];
    __shared__ int sh_base[16];
    __shared__ int sh_m, sh_b1, sh_k1, sh_npos, sh_istar, sh_kk, sh_cum;
    __shared__ unsigned sh_T, sh_pref;
    __shared__ float sh_mx;

    // npos_b from per-block partials (deterministic)
    int c0 = 0;
    for (int j = tid; j < NBX; j += SELT) c0 += partN[b * NBX + j];
    for (int off = 32; off > 0; off >>= 1) c0 += __shfl_down(c0, (unsigned)off, 64);
    if (lane == 0) redi[wid] = c0;
    __syncthreads();
    if (tid < 64) {
        int v = (tid < 16) ? redi[tid] : 0;
        for (int off = 32; off > 0; off >>= 1) v += __shfl_down(v, (unsigned)off, 64);
        if (tid == 0) sh_npos = v;
    }
    __syncthreads();
    int npos_b = sh_npos;
    long K = 3L * npos_b;
    if (K > P - 1) K = P - 1;

    // register-resident ce bits + packed pos bits; lc = pos ? 0 : ce
    unsigned cb[NCH];
    unsigned lv[NCH];
    unsigned pmw = 0u;
    const unsigned* ceb = (const unsigned*)ce + (size_t)b * P;
    const unsigned char* pb = posm + (size_t)b * P;
    #pragma unroll
    for (int c = 0; c < NCH; ++c) {
        int i = c * SELT + tid;
        unsigned cbits = (i < P) ? ceb[i] : 0u;
        bool ps = (i < P) && (pb[i] != 0);
        cb[c] = cbits;
        if (ps) pmw |= (1u << c);
        lv[c] = ps ? 0u : cbits;
    }

    unsigned uT = 0xFFFFFFFFu; int istar = -1;
    if (K > 0) {
        // batch max
        float mx = 0.f;
        #pragma unroll
        for (int c = 0; c < NCH; ++c) mx = fmaxf(mx, __uint_as_float(lv[c]));
        for (int off = 32; off > 0; off >>= 1) mx = fmaxf(mx, __shfl_xor(mx, off, 64));
        if (lane == 0) redf[wid] = mx;
        __syncthreads();
        if (tid == 0) {
            float v = redf[0];
            for (int w = 1; w < 16; ++w) v = fmaxf(v, redf[w]);
            sh_mx = v;
        }
        __syncthreads();
        float vmax = sh_mx;
        float scale = (vmax > 0.f) ? ((float)NB / vmax) : 0.f;

        // histogram (linear bins -> near-uniform, low contention)
        for (int j = tid; j < NB; j += SELT) hist[j] = 0u;
        __syncthreads();
        #pragma unroll
        for (int c = 0; c < NCH; ++c) {
            int i = c * SELT + tid;
            if (i < P) {
                int bn = (int)(__uint_as_float(lv[c]) * scale);
                if (bn > NB - 1) bn = NB - 1;
                atomicAdd(&hist[bn], 1u);
            }
        }
        __syncthreads();

        // suffix scan: suf(t) = sum of bins owned by threads > t  (4 bins/thread)
        int s4 = (int)(hist[4*tid] + hist[4*tid+1] + hist[4*tid+2] + hist[4*tid+3]);
        sums[SELT - 1 - tid] = s4;
        __syncthreads();
        int x = sums[tid];
        int xs = x;
        for (int off = 1; off < 64; off <<= 1) {
            int o = __shfl_up(xs, (unsigned)off, 64);
            if (lane >= off) xs += o;
        }
        if (lane == 63) redi[wid] = xs;
        __syncthreads();
        if (tid < 64) {
            int v = (tid < 16) ? redi[tid] : 0;
            int vs = v;
            for (int off = 1; off < 16; off <<= 1) {
                int o = __shfl_up(vs, (unsigned)off, 64);
                if (lane >= off) vs += o;
            }
            if (tid < 16) redi[tid] = vs - v;   // exclusive wave offsets
        }
        __syncthreads();
        int excl_rev = xs + redi[wid] - x;      // exclusive scan of reversed array at pos tid
        sums[tid] = excl_rev;
        __syncthreads();
        int suf = sums[SELT - 1 - tid];
        // locate K-th bin from the top within my 4 bins
        {
            int run = suf;
            for (int j = 3; j >= 0; --j) {
                int bin = 4 * tid + j;
                int h = (int)hist[bin];
                if ((long)run < K && K <= (long)run + h) { sh_b1 = bin; sh_k1 = (int)(K - run); }
                run += h;
            }
        }
        __syncthreads();
        int B1 = sh_b1, k1 = sh_k1;

        // gather candidates in bin B1
        if (tid == 0) sh_m = 0;
        __syncthreads();
        #pragma unroll
        for (int c = 0; c < NCH; ++c) {
            int i = c * SELT + tid;
            if (i < P) {
                float f = __uint_as_float(lv[c]);
                int bn = (int)(f * scale);
                if (bn > NB - 1) bn = NB - 1;
                if (bn == B1) {
                    int pos = atomicAdd(&sh_m, 1);
                    if (pos < CAP) { cv[pos] = f; ci[pos] = i; }
                }
            }
        }
        __syncthreads();
        int m = sh_m;
        if (m <= CAP) {
            // all-pairs exact rank (order-independent): find element with rank k1-1
            for (int j = tid; j < m; j += SELT) {
                float vj = cv[j]; int ij = ci[j]; int r = 0;
                for (int jj = 0; jj < m; ++jj) {
                    float vx = cv[jj];
                    r += (vx > vj || (vx == vj && ci[jj] < ij)) ? 1 : 0;
                }
                if (r == k1 - 1) { sh_T = __float_as_uint(vj); sh_istar = ij; }
            }
            __syncthreads();
            uT = sh_T; istar = sh_istar;
        } else {
            // fallback: full bit-serial radix (rare: extreme ties)
            if (tid == 0) { sh_pref = 0u; sh_kk = (int)K; }
            __syncthreads();
            for (int bit = 30; bit >= 0; --bit) {
                unsigned pref = sh_pref;
                int kk = sh_kk;
                unsigned hi = pref >> (bit + 1);
                int cnt = 0;
                #pragma unroll
                for (int c = 0; c < NCH; ++c) {
                    int i = c * SELT + tid;
                    unsigned v = lv[c];
                    cnt += ((i < P) && ((v >> (bit + 1)) == hi) && ((v >> bit) & 1u)) ? 1 : 0;
                }
                for (int off = 32; off > 0; off >>= 1) cnt += __shfl_down(cnt, (unsigned)off, 64);
                if (lane == 0) redi[wid] = cnt;
                __syncthreads();
                if (tid < 64) {
                    int v = (tid < 16) ? redi[tid] : 0;
                    for (int off = 32; off > 0; off >>= 1) v += __shfl_down(v, (unsigned)off, 64);
                    if (tid == 0) {
                        if (kk <= v) sh_pref = pref | (1u << bit);
                        else sh_kk = kk - v;
                    }
                }
                __syncthreads();
            }
            unsigned T = sh_pref; int krem = sh_kk;
            if (tid == 0) { sh_istar = -1; sh_cum = 0; }
            __syncthreads();
            for (int c = 0; c < NCH; ++c) {
                int i = c * SELT + tid;
                bool eq = (i < P) && (lv[c] == T);
                unsigned long long mk = __ballot(eq);
                if (lane == 0) redi[wid] = (int)__popcll(mk);
                __syncthreads();
                if (tid < 64) {
                    int v = (tid < 16) ? redi[tid] : 0;
                    for (int off = 1; off < 16; off <<= 1) {
                        int o = __shfl_up(v, (unsigned)off, 64);
                        if (lane >= off) v += o;
                    }
                    if (tid < 16) sh_base[tid] = v;
                }
                __syncthreads();
                int cum = sh_cum;
                int base = (wid == 0) ? 0 : sh_base[wid - 1];
                if (eq) {
                    int r = cum + base + (int)__popcll(mk & ((1ull << lane) - 1ull));
                    if (r == krem - 1) sh_istar = i;
                }
                __syncthreads();
                if (tid == 0) sh_cum = cum + sh_base[15];
                __syncthreads();
                if (sh_cum >= krem) break;
            }
            __syncthreads();
            uT = T; istar = sh_istar;
        }
    }

    // masked ce sum from registers (fixed-order tree)
    float cs = 0.f;
    #pragma unroll
    for (int c = 0; c < NCH; ++c) {
        int i = c * SELT + tid;
        if (i < P) {
            unsigned v = lv[c];
            bool sel = ((pmw >> c) & 1u) || (v > uT) || (v == uT && i <= istar);
            if (sel) cs += __uint_as_float(cb[c]);
        }
    }
    for (int off = 32; off > 0; off >>= 1) cs += __shfl_down(cs, (unsigned)off, 64);
    if (lane == 0) redf[wid] = cs;
    __syncthreads();
    if (tid < 64) {
        float v = (tid < 16) ? redf[tid] : 0.f;
        for (int off = 32; off > 0; off >>= 1) v += __shfl_down(v, (unsigned)off, 64);
        if (tid == 0) { partC[b] = v; npos[b] = npos_b; }
    }
}

// ---------------- final deterministic reduce + divide ----------------
__global__ void k_final(const float* __restrict__ partL, const float* __restrict__ partC,
                        const int* __restrict__ npos, int nPart,
                        float* __restrict__ out, int B) {
    __shared__ float sL[256];
    __shared__ float sC[256];
    __shared__ int   sN[256];
    int tid = threadIdx.x;
    float aL = 0.f, aC = 0.f; int aN = 0;
    for (int i = tid; i < nPart; i += 256) aL += partL[i];
    for (int i = tid; i < B; i += 256) { aC += partC[i]; aN += npos[i]; }
    sL[tid] = aL; sC[tid] = aC; sN[tid] = aN;
    __syncthreads();
    for (int off = 128; off > 0; off >>= 1) {
        if (tid < off) { sL[tid] += sL[tid+off]; sC[tid] += sC[tid+off]; sN[tid] += sN[tid+off]; }
        __syncthreads();
    }
    if (tid == 0) {
        float N = (float)sN[0];
        out[0] = sL[0] / N;
        out[1] = sC[0] / N;
    }
}

extern "C" void kernel_launch(void* const* d_in, const int* in_sizes, int n_in,
                              void* d_out, int out_size, void* d_ws, size_t ws_size,
                              hipStream_t stream) {
    const float* arm_loc  = (const float*)d_in[0];
    const float* arm_conf = (const float*)d_in[1];
    const float* odm_loc  = (const float*)d_in[2];
    const float* odm_conf = (const float*)d_in[3];
    const float* priors   = (const float*)d_in[4];
    const float* targets  = (const float*)d_in[5];
    const int*   num_gts  = (const int*)d_in[6];
    float* out = (float*)d_out;

    int B = in_sizes[6];
    int P = in_sizes[4] / 4;
    int C = in_sizes[3] / (B * P);
    int G = in_sizes[5] / (B * 5);
    int NBX = (P + BLK - 1) / BLK;

    char* ws = (char*)d_ws;
    size_t off = 0;
    auto alloc = [&](size_t bytes) -> void* {
        void* ptr = ws + off;
        off = (off + bytes + 255) & ~(size_t)255;
        return ptr;
    };
    unsigned long long* bt  = (unsigned long long*)alloc((size_t)B * P * 8);
    unsigned long long* bpw = (unsigned long long*)alloc((size_t)B * G * NBX * 8);
    float* ce  = (float*)alloc((size_t)B * P * sizeof(float));
    unsigned char* posm = (unsigned char*)alloc((size_t)B * P);
    float* partL = (float*)alloc((size_t)B * NBX * sizeof(float));
    int* partN   = (int*)alloc((size_t)B * NBX * sizeof(int));
    float* partC = (float*)alloc((size_t)B * sizeof(float));
    int* npos    = (int*)alloc((size_t)B * sizeof(int));

    k_iou<<<dim3(NBX, B), BLK, 0, stream>>>(arm_loc, priors, targets, num_gts, bt, bpw, B, P, G);
    k_fix<<<dim3(G, B), 64, 0, stream>>>(num_gts, bpw, bt, B, P, G, NBX);
    k_main<<<dim3(NBX, B), BLK, 0, stream>>>(arm_loc, priors, arm_conf, odm_loc, odm_conf, targets,
                                             bt, ce, posm, partL, partN, B, P, C, G);
    k_select<<<B, SELT, 0, stream>>>(ce, posm, partN, NBX, partC, npos, P);
    k_final<<<1, 256, 0, stream>>>(partL, partC, npos, B * NBX, out, B);
}